// Round 1
// baseline (1199.423 us; speedup 1.0000x reference)
//
#include <hip/hip_runtime.h>
#include <hip/hip_bf16.h>
#include <math.h>

// Problem constants (query_len=3584 fixed => win_num=512, per_win=8, win*WIN=3584)
#define B_    8
#define M_    4096
#define D_    512
#define H_    8
#define HD_   64
#define WIN_  7
#define WN_   512
#define MQ_   3584
#define SCALE_ 0.04419417382415922f   // 512^-0.5
#define EPS_  1e-5f

// ---------------------------------------------------------------------------
// Generic tiled fp32 GEMM: C = A(rows x 512) @ W(512 x 512) + bias
// 128x128 tile, BK=16, 256 threads, 8x8 per thread as 2x2 quadrants of 4x4.
// blockIdx.z selects one of up to 3 (A,W,bias,C) sets.
// ---------------------------------------------------------------------------
__global__ __launch_bounds__(256) void gemm_f32(
    const float* A0, const float* W0, const float* b0, float* C0,
    const float* A1, const float* W1, const float* b1, float* C1,
    const float* A2, const float* W2, const float* b2, float* C2)
{
  const float *A, *W, *bias; float *C;
  if (blockIdx.z == 0)      { A = A0; W = W0; bias = b0; C = C0; }
  else if (blockIdx.z == 1) { A = A1; W = W1; bias = b1; C = C1; }
  else                      { A = A2; W = W2; bias = b2; C = C2; }

  const int m0 = blockIdx.x * 128;
  const int n0 = blockIdx.y * 128;

  __shared__ float As[16][132];   // [k][m], padded
  __shared__ float Bs[16][132];   // [k][n], padded

  const int tid = threadIdx.x;
  const int tr = tid >> 4, tc = tid & 15;
  const int r0 = tr * 4, c0 = tc * 4;

  float acc[8][8];
#pragma unroll
  for (int i = 0; i < 8; ++i)
#pragma unroll
    for (int j = 0; j < 8; ++j) acc[i][j] = 0.0f;

  for (int k0 = 0; k0 < 512; k0 += 16) {
    __syncthreads();
    // A tile: 128 rows x 16 k  (512 float4, 2/thread), transpose into As[k][m]
#pragma unroll
    for (int l = 0; l < 2; ++l) {
      int L = tid + l * 256;
      int m = L >> 2, kv = L & 3;
      float4 v = *reinterpret_cast<const float4*>(A + (size_t)(m0 + m) * 512 + k0 + kv * 4);
      As[kv * 4 + 0][m] = v.x;
      As[kv * 4 + 1][m] = v.y;
      As[kv * 4 + 2][m] = v.z;
      As[kv * 4 + 3][m] = v.w;
    }
    // B tile: 16 k x 128 n (512 float4, 2/thread), direct copy
#pragma unroll
    for (int l = 0; l < 2; ++l) {
      int L = tid + l * 256;
      int kr = L >> 5, nv = L & 31;
      float4 v = *reinterpret_cast<const float4*>(W + (size_t)(k0 + kr) * 512 + n0 + nv * 4);
      *reinterpret_cast<float4*>(&Bs[kr][nv * 4]) = v;
    }
    __syncthreads();

#pragma unroll
    for (int kk = 0; kk < 16; ++kk) {
      float4 alo = *reinterpret_cast<const float4*>(&As[kk][r0]);
      float4 ahi = *reinterpret_cast<const float4*>(&As[kk][r0 + 64]);
      float4 blo = *reinterpret_cast<const float4*>(&Bs[kk][c0]);
      float4 bhi = *reinterpret_cast<const float4*>(&Bs[kk][c0 + 64]);
      float a[8] = {alo.x, alo.y, alo.z, alo.w, ahi.x, ahi.y, ahi.z, ahi.w};
      float b[8] = {blo.x, blo.y, blo.z, blo.w, bhi.x, bhi.y, bhi.z, bhi.w};
#pragma unroll
      for (int i = 0; i < 8; ++i)
#pragma unroll
        for (int j = 0; j < 8; ++j)
          acc[i][j] = fmaf(a[i], b[j], acc[i][j]);
    }
  }

  // epilogue
#pragma unroll
  for (int i = 0; i < 8; ++i) {
    int m = m0 + ((i < 4) ? (r0 + i) : (64 + r0 + i - 4));
#pragma unroll
    for (int half = 0; half < 2; ++half) {
      int n = n0 + half * 64 + c0;
      float4 bv = *reinterpret_cast<const float4*>(bias + n);
      float4 o;
      o.x = acc[i][half * 4 + 0] + bv.x;
      o.y = acc[i][half * 4 + 1] + bv.y;
      o.z = acc[i][half * 4 + 2] + bv.z;
      o.w = acc[i][half * 4 + 3] + bv.w;
      *reinterpret_cast<float4*>(C + (size_t)m * 512 + n) = o;
    }
  }
}

// ---------------------------------------------------------------------------
// Window attention, fused q 5-tap smoothing. One 64-thread block per (h,w,b).
// Tokens m = 8w..8w+7, dims h*64..h*64+63. Softmax over 8 keys, scale 1/sqrt(512).
// ---------------------------------------------------------------------------
__global__ __launch_bounds__(64) void attn_win(
    const float* kp, const float* vp, const float* qp0, float* attn)
{
  const int h = blockIdx.x, w = blockIdx.y, b = blockIdx.z;
  const int t = threadIdx.x;

  __shared__ float ks[8][68], vs[8][68], qr[12][68], qs[8][68], Ps[8][9];

  const size_t base = ((size_t)b * M_ + (size_t)w * 8) * D_ + h * 64;

  // load k, v: 8 rows x 64 = 128 float4, 2/thread
#pragma unroll
  for (int l = 0; l < 2; ++l) {
    int L = t + l * 64;
    int i = L >> 4, dv = L & 15;
    float4 kv4 = *reinterpret_cast<const float4*>(kp + base + (size_t)i * D_ + dv * 4);
    float4 vv4 = *reinterpret_cast<const float4*>(vp + base + (size_t)i * D_ + dv * 4);
    *reinterpret_cast<float4*>(&ks[i][dv * 4]) = kv4;
    *reinterpret_cast<float4*>(&vs[i][dv * 4]) = vv4;
  }
  // load q raw rows m = 8w-2 .. 8w+9 (zero outside [0,M))
#pragma unroll
  for (int l = 0; l < 3; ++l) {
    int L = t + l * 64;
    int i = L >> 4, dv = L & 15;
    int m = w * 8 - 2 + i;
    float4 v = make_float4(0.f, 0.f, 0.f, 0.f);
    if (m >= 0 && m < M_)
      v = *reinterpret_cast<const float4*>(qp0 + ((size_t)b * M_ + m) * D_ + h * 64 + dv * 4);
    *reinterpret_cast<float4*>(&qr[i][dv * 4]) = v;
  }
  __syncthreads();

  // smooth: qs[j][d] = mean of qr[j..j+4][d], d = lane
#pragma unroll
  for (int j = 0; j < 8; ++j)
    qs[j][t] = 0.2f * (qr[j][t] + qr[j + 1][t] + qr[j + 2][t] + qr[j + 3][t] + qr[j + 4][t]);
  __syncthreads();

  // scores: lane (i = t>>3 query, j = t&7 key)
  const int qi = t >> 3, kj = t & 7;
  float s = 0.0f;
#pragma unroll
  for (int d = 0; d < 64; ++d) s = fmaf(qs[qi][d], ks[kj][d], s);
  s *= SCALE_;

  // softmax within 8-lane group
  float mx = s;
  mx = fmaxf(mx, __shfl_xor(mx, 1));
  mx = fmaxf(mx, __shfl_xor(mx, 2));
  mx = fmaxf(mx, __shfl_xor(mx, 4));
  float e = expf(s - mx);
  float sum = e;
  sum += __shfl_xor(sum, 1);
  sum += __shfl_xor(sum, 2);
  sum += __shfl_xor(sum, 4);
  float p = e / sum;
  Ps[qi][kj] = p;
  __syncthreads();

  // PV: lane computes out[qi][kj*8 + c], c=0..7
  float o[8];
#pragma unroll
  for (int c = 0; c < 8; ++c) o[c] = 0.0f;
#pragma unroll
  for (int tt = 0; tt < 8; ++tt) {
    float pw = Ps[qi][tt];
#pragma unroll
    for (int c = 0; c < 8; ++c) o[c] = fmaf(pw, vs[tt][kj * 8 + c], o[c]);
  }
  float4 o0 = make_float4(o[0], o[1], o[2], o[3]);
  float4 o1 = make_float4(o[4], o[5], o[6], o[7]);
  *reinterpret_cast<float4*>(attn + base + (size_t)qi * D_ + kj * 8) = o0;
  *reinterpret_cast<float4*>(attn + base + (size_t)qi * D_ + kj * 8 + 4) = o1;
}

// ---------------------------------------------------------------------------
// LayerNorm + exact GELU on window token 0. One wave per (b,w) row.
// ---------------------------------------------------------------------------
__global__ __launch_bounds__(64) void ln_gelu(
    const float* attn, const float* g, const float* be, float* wt)
{
  const int r = blockIdx.x;            // r = b*512 + w
  const int b = r >> 9, w = r & 511;
  const int t = threadIdx.x;
  const float* x = attn + (((size_t)b * M_) + (size_t)w * 8) * D_;

  float4 v0 = *reinterpret_cast<const float4*>(x + 4 * t);
  float4 v1 = *reinterpret_cast<const float4*>(x + 256 + 4 * t);

  float s1 = v0.x + v0.y + v0.z + v0.w + v1.x + v1.y + v1.z + v1.w;
  float s2 = v0.x * v0.x + v0.y * v0.y + v0.z * v0.z + v0.w * v0.w +
             v1.x * v1.x + v1.y * v1.y + v1.z * v1.z + v1.w * v1.w;
#pragma unroll
  for (int off = 1; off < 64; off <<= 1) {
    s1 += __shfl_xor(s1, off);
    s2 += __shfl_xor(s2, off);
  }
  const float mu  = s1 * (1.0f / 512.0f);
  const float var = s2 * (1.0f / 512.0f) - mu * mu;
  const float inv = 1.0f / sqrtf(var + EPS_);

  float* wrow = wt + (size_t)r * D_;
  const float k2 = 0.70710678118654752f;
#pragma unroll
  for (int half = 0; half < 2; ++half) {
    float4 v = half ? v1 : v0;
    int d = half * 256 + 4 * t;
    float4 gv = *reinterpret_cast<const float4*>(g + d);
    float4 bv = *reinterpret_cast<const float4*>(be + d);
    float y0 = (v.x - mu) * inv * gv.x + bv.x;
    float y1 = (v.y - mu) * inv * gv.y + bv.y;
    float y2 = (v.z - mu) * inv * gv.z + bv.z;
    float y3 = (v.w - mu) * inv * gv.w + bv.w;
    float4 o;
    o.x = 0.5f * y0 * (1.0f + erff(y0 * k2));
    o.y = 0.5f * y1 * (1.0f + erff(y1 * k2));
    o.z = 0.5f * y2 * (1.0f + erff(y2 * k2));
    o.w = 0.5f * y3 * (1.0f + erff(y3 * k2));
    *reinterpret_cast<float4*>(wrow + d) = o;
  }
}

// ---------------------------------------------------------------------------
// expS[bh][wq][wk] = exp(SCALE * pq_h[wq] . pk_h[wk]), K=64. 64x64 tile/block.
// ---------------------------------------------------------------------------
__global__ __launch_bounds__(256) void qk_exp(
    const float* pq, const float* pk, float* expS)
{
  const int bh = blockIdx.z;
  const int b = bh >> 3, h = bh & 7;
  const int wq0 = blockIdx.x * 64, wk0 = blockIdx.y * 64;
  const int tid = threadIdx.x;

  __shared__ float Aq[64][68];  // [kd][wq]
  __shared__ float Bk[64][68];  // [kd][wk]

#pragma unroll
  for (int l = 0; l < 4; ++l) {
    int L = tid + l * 256;
    int row = L >> 4, dv = L & 15;
    float4 a = *reinterpret_cast<const float4*>(pq + ((size_t)b * WN_ + wq0 + row) * D_ + h * 64 + dv * 4);
    float4 c = *reinterpret_cast<const float4*>(pk + ((size_t)b * WN_ + wk0 + row) * D_ + h * 64 + dv * 4);
    Aq[dv * 4 + 0][row] = a.x; Aq[dv * 4 + 1][row] = a.y;
    Aq[dv * 4 + 2][row] = a.z; Aq[dv * 4 + 3][row] = a.w;
    Bk[dv * 4 + 0][row] = c.x; Bk[dv * 4 + 1][row] = c.y;
    Bk[dv * 4 + 2][row] = c.z; Bk[dv * 4 + 3][row] = c.w;
  }
  __syncthreads();

  const int r0 = (tid >> 4) * 4, c0 = (tid & 15) * 4;
  float acc[4][4];
#pragma unroll
  for (int i = 0; i < 4; ++i)
#pragma unroll
    for (int j = 0; j < 4; ++j) acc[i][j] = 0.0f;

#pragma unroll
  for (int kk = 0; kk < 64; ++kk) {
    float4 a = *reinterpret_cast<const float4*>(&Aq[kk][r0]);
    float4 c = *reinterpret_cast<const float4*>(&Bk[kk][c0]);
    float av[4] = {a.x, a.y, a.z, a.w};
    float cv[4] = {c.x, c.y, c.z, c.w};
#pragma unroll
    for (int i = 0; i < 4; ++i)
#pragma unroll
      for (int j = 0; j < 4; ++j)
        acc[i][j] = fmaf(av[i], cv[j], acc[i][j]);
  }

#pragma unroll
  for (int i = 0; i < 4; ++i) {
    float4 o;
    o.x = expf(acc[i][0] * SCALE_);
    o.y = expf(acc[i][1] * SCALE_);
    o.z = expf(acc[i][2] * SCALE_);
    o.w = expf(acc[i][3] * SCALE_);
    *reinterpret_cast<float4*>(expS + ((size_t)bh * WN_ + wq0 + r0 + i) * WN_ + wk0 + c0) = o;
  }
}

// ---------------------------------------------------------------------------
// rsinv[row] = 1 / sum_k expS[row][k]   (row = bh*512 + wq), one wave per row.
// ---------------------------------------------------------------------------
__global__ __launch_bounds__(64) void rs_inv(const float* expS, float* rsinv)
{
  const int row = blockIdx.x;
  const int t = threadIdx.x;
  const float* x = expS + (size_t)row * WN_;
  float4 v0 = *reinterpret_cast<const float4*>(x + 4 * t);
  float4 v1 = *reinterpret_cast<const float4*>(x + 256 + 4 * t);
  float s = v0.x + v0.y + v0.z + v0.w + v1.x + v1.y + v1.z + v1.w;
#pragma unroll
  for (int off = 1; off < 64; off <<= 1) s += __shfl_xor(s, off);
  if (t == 0) rsinv[row] = 1.0f / s;
}

// ---------------------------------------------------------------------------
// pout GEMM + residual: X2[b][wq*7+t][h*64+d] =
//   sum_w2 (expS[bh][wq][w2]*rsinv) * attn[b][8*w2+t+1][h*64+d]  + attn[b][8*wq+t+1][h*64+d]
// 64(wq) x 64(d) tile; blockIdx.y = t (0..6); K=512 in BK=32 chunks.
// ---------------------------------------------------------------------------
__global__ __launch_bounds__(256) void pv_gemm(
    const float* expS, const float* rsinv, const float* attn, float* X2)
{
  const int bh = blockIdx.z;
  const int b = bh >> 3, h = bh & 7;
  const int wq0 = blockIdx.x * 64;
  const int t = blockIdx.y;
  const int tid = threadIdx.x;

  __shared__ float Pst[32][68];  // [k][wq]
  __shared__ float Vs[32][68];   // [k][d]

  const int tr = tid >> 4, tc = tid & 15;
  const int r0 = tr * 4, c0 = tc * 4;
  float acc[4][4];
#pragma unroll
  for (int i = 0; i < 4; ++i)
#pragma unroll
    for (int j = 0; j < 4; ++j) acc[i][j] = 0.0f;

  for (int k0 = 0; k0 < 512; k0 += 32) {
    __syncthreads();
    // P tile: 64 wq-rows x 32 k (512 float4, 2/thread), * rsinv, transposed
#pragma unroll
    for (int l = 0; l < 2; ++l) {
      int L = tid + l * 256;
      int row = L >> 3, kv = L & 7;
      float4 v = *reinterpret_cast<const float4*>(expS + ((size_t)bh * WN_ + wq0 + row) * WN_ + k0 + kv * 4);
      float ri = rsinv[(size_t)bh * WN_ + wq0 + row];
      Pst[kv * 4 + 0][row] = v.x * ri;
      Pst[kv * 4 + 1][row] = v.y * ri;
      Pst[kv * 4 + 2][row] = v.z * ri;
      Pst[kv * 4 + 3][row] = v.w * ri;
    }
    // V tile: 32 keys x 64 dims (gathered rows of attn)
#pragma unroll
    for (int l = 0; l < 2; ++l) {
      int L = tid + l * 256;
      int kr = L >> 4, nv = L & 15;
      float4 v = *reinterpret_cast<const float4*>(
          attn + ((size_t)b * M_ + (size_t)(k0 + kr) * 8 + t + 1) * D_ + h * 64 + nv * 4);
      *reinterpret_cast<float4*>(&Vs[kr][nv * 4]) = v;
    }
    __syncthreads();

#pragma unroll
    for (int kk = 0; kk < 32; ++kk) {
      float4 a = *reinterpret_cast<const float4*>(&Pst[kk][r0]);
      float4 c = *reinterpret_cast<const float4*>(&Vs[kk][c0]);
      float av[4] = {a.x, a.y, a.z, a.w};
      float cv[4] = {c.x, c.y, c.z, c.w};
#pragma unroll
      for (int i = 0; i < 4; ++i)
#pragma unroll
        for (int j = 0; j < 4; ++j)
          acc[i][j] = fmaf(av[i], cv[j], acc[i][j]);
    }
  }

#pragma unroll
  for (int i = 0; i < 4; ++i) {
    int wq = wq0 + r0 + i;
    size_t arow = ((size_t)b * M_ + (size_t)wq * 8 + t + 1) * D_ + h * 64;
    size_t xrow = ((size_t)b * MQ_ + (size_t)wq * 7 + t) * D_ + h * 64;
    float4 res = *reinterpret_cast<const float4*>(attn + arow + c0);
    float4 o;
    o.x = acc[i][0] + res.x;
    o.y = acc[i][1] + res.y;
    o.z = acc[i][2] + res.z;
    o.w = acc[i][3] + res.w;
    *reinterpret_cast<float4*>(X2 + xrow + c0) = o;
  }
}

// ---------------------------------------------------------------------------
extern "C" void kernel_launch(void* const* d_in, const int* in_sizes, int n_in,
                              void* d_out, int out_size, void* d_ws, size_t ws_size,
                              hipStream_t stream)
{
  const float* k_in = (const float*)d_in[0];
  const float* v_in = (const float*)d_in[1];
  const float* q_in = (const float*)d_in[2];
  // d_in[3] = query_len (3584, constant)
  const float* Wk  = (const float*)d_in[4];
  const float* bk  = (const float*)d_in[5];
  const float* Wv  = (const float*)d_in[6];
  const float* bv  = (const float*)d_in[7];
  const float* Wq  = (const float*)d_in[8];
  const float* bq  = (const float*)d_in[9];
  const float* lng = (const float*)d_in[10];
  const float* lnb = (const float*)d_in[11];
  const float* Wpq = (const float*)d_in[12];
  const float* bpq = (const float*)d_in[13];
  const float* Wpk = (const float*)d_in[14];
  const float* bpk = (const float*)d_in[15];
  const float* Wo  = (const float*)d_in[16];
  const float* bo  = (const float*)d_in[17];
  float* out = (float*)d_out;

  // Workspace layout (floats). Peak = 4 slots of 16,777,216 = 256 MiB.
  float* ws = (float*)d_ws;
  float* kp   = ws;                     // slot0
  float* vp   = ws + 16777216;          // slot1
  float* qp0  = ws + 33554432;          // slot2
  float* attn = ws + 50331648;          // slot3
  // After attn_win: kp/vp/qp0 slots are dead -> reuse:
  float* wt    = ws;                    // 2,097,152 (slot0)
  float* pq    = ws + 2097152;          //            (slot0)
  float* pk    = ws + 4194304;          //            (slot0)
  float* rsinv = ws + 6291456;          // 32,768     (slot0)
  float* expS  = ws + 16777216;         // slot1 (vp dead)
  float* X2    = ws + 33554432;         // slot2 (qp0 dead), 14,680,064

  // 1. projections k,v,q   (32768 x 512 @ 512 x 512) x3
  gemm_f32<<<dim3(256, 4, 3), 256, 0, stream>>>(
      k_in, Wk, bk, kp,  v_in, Wv, bv, vp,  q_in, Wq, bq, qp0);
  // 2. window attention (+ fused q smoothing)
  attn_win<<<dim3(8, 512, 8), 64, 0, stream>>>(kp, vp, qp0, attn);
  // 3. LN + GELU on window token 0
  ln_gelu<<<4096, 64, 0, stream>>>(attn, lng, lnb, wt);
  // 4. pq, pk projections (4096 x 512 @ 512 x 512) x2
  gemm_f32<<<dim3(32, 4, 2), 256, 0, stream>>>(
      wt, Wpq, bpq, pq,  wt, Wpk, bpk, pk,  wt, Wpq, bpq, pq);
  // 5. exp(scores)
  qk_exp<<<dim3(8, 8, 64), 256, 0, stream>>>(pq, pk, expS);
  // 6. inverse row sums
  rs_inv<<<32768, 64, 0, stream>>>(expS, rsinv);
  // 7. P @ pv + residual -> X2
  pv_gemm<<<dim3(8, 7, 64), 256, 0, stream>>>(expS, rsinv, attn, X2);
  // 8. final projection (28672 x 512 @ 512 x 512)
  gemm_f32<<<dim3(224, 4, 1), 256, 0, stream>>>(
      X2, Wo, bo, out,  X2, Wo, bo, out,  X2, Wo, bo, out);
}

// Round 2
// 384.541 us; speedup vs baseline: 3.1191x; 3.1191x over previous
//
#include <hip/hip_runtime.h>
#include <hip/hip_bf16.h>
#include <math.h>

#define SCALE_ 0.04419417382415922f   // 512^-0.5
#define EPS_  1e-5f

typedef unsigned short u16;
typedef __attribute__((ext_vector_type(8))) short     bf16x8;
typedef __attribute__((ext_vector_type(4))) float     f32x4;
typedef __attribute__((ext_vector_type(8))) unsigned short u16x8;
typedef __attribute__((ext_vector_type(4))) unsigned short u16x4;

__device__ __forceinline__ u16 f2b(float f) {
  union { float f; unsigned int u; } x; x.f = f;
  unsigned int u = x.u;
  return (u16)((u + 0x7FFFu + ((u >> 16) & 1u)) >> 16);
}
__device__ __forceinline__ float b2f(u16 h) {
  union { unsigned int u; float f; } x; x.u = ((unsigned int)h) << 16;
  return x.f;
}
__device__ __forceinline__ void gload_lds16(const void* g, void* l) {
  __builtin_amdgcn_global_load_lds(
      (const __attribute__((address_space(1))) void*)g,
      (__attribute__((address_space(3))) void*)l, 16, 0, 0);
}

// ---------------------------------------------------------------------------
// Weight convert+transpose: Wt[n][k] = bf16(W[k][n]), 512x512, z selects weight
// ---------------------------------------------------------------------------
__global__ __launch_bounds__(256) void wconv(
    const float* W0, const float* W1, const float* W2,
    const float* W3, const float* W4, const float* W5, u16* wt)
{
  const float* W;
  switch (blockIdx.z) {
    case 0: W = W0; break; case 1: W = W1; break; case 2: W = W2; break;
    case 3: W = W3; break; case 4: W = W4; break; default: W = W5; break;
  }
  u16* Wt = wt + (size_t)blockIdx.z * 262144;
  const int k0 = blockIdx.x * 64, n0 = blockIdx.y * 64;
  __shared__ float T[64][68];
  const int tid = threadIdx.x;
#pragma unroll
  for (int it = 0; it < 4; ++it) {
    int L = it * 256 + tid;
    int r = L >> 4, cg = L & 15;
    float4 v = *reinterpret_cast<const float4*>(W + (size_t)(k0 + r) * 512 + n0 + cg * 4);
    T[r][cg * 4 + 0] = v.x; T[r][cg * 4 + 1] = v.y;
    T[r][cg * 4 + 2] = v.z; T[r][cg * 4 + 3] = v.w;
  }
  __syncthreads();
#pragma unroll
  for (int it = 0; it < 2; ++it) {
    int L = it * 256 + tid;
    int rn = L >> 3, kg = L & 7;
    u16x8 o;
#pragma unroll
    for (int e = 0; e < 8; ++e) o[e] = f2b(T[kg * 8 + e][rn]);
    *(u16x8*)(Wt + (size_t)(n0 + rn) * 512 + k0 + kg * 8) = o;
  }
}

// ---------------------------------------------------------------------------
// fp32 -> bf16 convert for k, v, q inputs (z selects tensor, 16,777,216 each)
// ---------------------------------------------------------------------------
__global__ __launch_bounds__(256) void inconv(
    const float* s0, const float* s1, const float* s2,
    u16* d0, u16* d1, u16* d2)
{
  const float* s; u16* d;
  if (blockIdx.z == 0)      { s = s0; d = d0; }
  else if (blockIdx.z == 1) { s = s1; d = d1; }
  else                      { s = s2; d = d2; }
  size_t i = ((size_t)blockIdx.x * 256 + threadIdx.x) * 8;
  float4 a = *reinterpret_cast<const float4*>(s + i);
  float4 b = *reinterpret_cast<const float4*>(s + i + 4);
  u16x8 o;
  o[0] = f2b(a.x); o[1] = f2b(a.y); o[2] = f2b(a.z); o[3] = f2b(a.w);
  o[4] = f2b(b.x); o[5] = f2b(b.y); o[6] = f2b(b.z); o[7] = f2b(b.w);
  *(u16x8*)(d + i) = o;
}

// ---------------------------------------------------------------------------
// bf16 MFMA GEMM: C[M x 512] = A[M x 512] @ Bt^T + bias.  Bt is [n][k].
// 128x128 tile, BK=64, 4 waves each 64x64 (4x4 frags of 16x16x32).
// XOR-swizzled LDS (16B slot s = c ^ (row&7)), global_load_lds w16 staging.
// ---------------------------------------------------------------------------
__global__ __launch_bounds__(256) void gemm_bf16(
    const u16* __restrict__ A, const u16* __restrict__ Bt,
    const float* __restrict__ bias, void* __restrict__ Cout, int outf32)
{
  __shared__ u16 As[8192];   // 128 x 64
  __shared__ u16 Bs[8192];   // 128 x 64
  const int tid = threadIdx.x;
  const int lane = tid & 63, wid = tid >> 6;
  const int wr = wid >> 1, wc = wid & 1;
  const int l15 = lane & 15, lh = lane >> 4, l7 = lane & 7;
  const int m0 = blockIdx.x * 128, n0 = blockIdx.y * 128;

  const f32x4 fz = {0.f, 0.f, 0.f, 0.f};
  f32x4 acc[4][4];
#pragma unroll
  for (int m = 0; m < 4; ++m)
#pragma unroll
    for (int n = 0; n < 4; ++n) acc[m][n] = fz;

  int aoff[2], boff[2];
#pragma unroll
  for (int kh = 0; kh < 2; ++kh) {
    int slot = ((kh * 4 + lh) ^ l7) << 4;
    aoff[kh] = (wr * 64 + l15) * 128 + slot;
    boff[kh] = (wc * 64 + l15) * 128 + slot;
  }

  for (int k0 = 0; k0 < 512; k0 += 64) {
    __syncthreads();
#pragma unroll
    for (int it = 0; it < 4; ++it) {
      int L = it * 256 + tid;
      int r = L >> 3, s = L & 7;
      int c = s ^ (r & 7);
      const u16* ga = A  + (size_t)(m0 + r) * 512 + k0 + c * 8;
      const u16* gb = Bt + (size_t)(n0 + r) * 512 + k0 + c * 8;
      char* la = (char*)As + (it * 256 + wid * 64) * 16;
      char* lb = (char*)Bs + (it * 256 + wid * 64) * 16;
      gload_lds16(ga, la);
      gload_lds16(gb, lb);
    }
    __syncthreads();
#pragma unroll
    for (int kh = 0; kh < 2; ++kh) {
      bf16x8 af[4], bfr[4];
#pragma unroll
      for (int m = 0; m < 4; ++m)
        af[m] = *(const bf16x8*)((const char*)As + aoff[kh] + m * 2048);
#pragma unroll
      for (int n = 0; n < 4; ++n)
        bfr[n] = *(const bf16x8*)((const char*)Bs + boff[kh] + n * 2048);
#pragma unroll
      for (int m = 0; m < 4; ++m)
#pragma unroll
        for (int n = 0; n < 4; ++n)
          acc[m][n] = __builtin_amdgcn_mfma_f32_16x16x32_bf16(af[m], bfr[n], acc[m][n], 0, 0, 0);
    }
  }

  const int gn0 = n0 + wc * 64 + l15;
  float bv[4];
#pragma unroll
  for (int n = 0; n < 4; ++n) bv[n] = bias[gn0 + n * 16];

  if (outf32) {
    float* C = (float*)Cout;
#pragma unroll
    for (int m = 0; m < 4; ++m)
#pragma unroll
      for (int reg = 0; reg < 4; ++reg) {
        int gm = m0 + wr * 64 + m * 16 + lh * 4 + reg;
#pragma unroll
        for (int n = 0; n < 4; ++n)
          C[(size_t)gm * 512 + gn0 + n * 16] = acc[m][n][reg] + bv[n];
      }
  } else {
    u16* C = (u16*)Cout;
#pragma unroll
    for (int m = 0; m < 4; ++m)
#pragma unroll
      for (int reg = 0; reg < 4; ++reg) {
        int gm = m0 + wr * 64 + m * 16 + lh * 4 + reg;
#pragma unroll
        for (int n = 0; n < 4; ++n)
          C[(size_t)gm * 512 + gn0 + n * 16] = f2b(acc[m][n][reg] + bv[n]);
      }
  }
}

// ---------------------------------------------------------------------------
// Window attention (bf16 in/out), fused q 5-tap smoothing. fp32 math.
// ---------------------------------------------------------------------------
__global__ __launch_bounds__(64) void attn_win(
    const u16* kp, const u16* vp, const u16* qp0, u16* attn)
{
  const int h = blockIdx.x, w = blockIdx.y, b = blockIdx.z;
  const int t = threadIdx.x;
  __shared__ float ks[8][68], vs[8][68], qr[12][68], qs[8][68], Ps[8][9];
  const size_t base = ((size_t)b * 4096 + (size_t)w * 8) * 512 + h * 64;

  {
    int i = t >> 3, dg = t & 7;
    u16x8 kv = *(const u16x8*)(kp + base + (size_t)i * 512 + dg * 8);
    u16x8 vv = *(const u16x8*)(vp + base + (size_t)i * 512 + dg * 8);
#pragma unroll
    for (int e = 0; e < 8; ++e) {
      ks[i][dg * 8 + e] = b2f(kv[e]);
      vs[i][dg * 8 + e] = b2f(vv[e]);
    }
  }
#pragma unroll
  for (int l = 0; l < 2; ++l) {
    int L = t + l * 64;
    if (L < 96) {
      int i = L >> 3, dg = L & 7;
      int m = w * 8 - 2 + i;
      if (m >= 0 && m < 4096) {
        u16x8 qv = *(const u16x8*)(qp0 + ((size_t)b * 4096 + m) * 512 + h * 64 + dg * 8);
#pragma unroll
        for (int e = 0; e < 8; ++e) qr[i][dg * 8 + e] = b2f(qv[e]);
      } else {
#pragma unroll
        for (int e = 0; e < 8; ++e) qr[i][dg * 8 + e] = 0.0f;
      }
    }
  }
  __syncthreads();
#pragma unroll
  for (int j = 0; j < 8; ++j)
    qs[j][t] = 0.2f * (qr[j][t] + qr[j + 1][t] + qr[j + 2][t] + qr[j + 3][t] + qr[j + 4][t]);
  __syncthreads();

  const int qi = t >> 3, kj = t & 7;
  float s = 0.0f;
#pragma unroll
  for (int d = 0; d < 64; ++d) s = fmaf(qs[qi][d], ks[kj][d], s);
  s *= SCALE_;
  float mx = s;
  mx = fmaxf(mx, __shfl_xor(mx, 1));
  mx = fmaxf(mx, __shfl_xor(mx, 2));
  mx = fmaxf(mx, __shfl_xor(mx, 4));
  float e = expf(s - mx);
  float sum = e;
  sum += __shfl_xor(sum, 1);
  sum += __shfl_xor(sum, 2);
  sum += __shfl_xor(sum, 4);
  Ps[qi][kj] = e / sum;
  __syncthreads();

  float o[8];
#pragma unroll
  for (int c = 0; c < 8; ++c) o[c] = 0.0f;
#pragma unroll
  for (int tt = 0; tt < 8; ++tt) {
    float pw = Ps[qi][tt];
#pragma unroll
    for (int c = 0; c < 8; ++c) o[c] = fmaf(pw, vs[tt][kj * 8 + c], o[c]);
  }
  u16x8 ov;
#pragma unroll
  for (int c = 0; c < 8; ++c) ov[c] = f2b(o[c]);
  *(u16x8*)(attn + base + (size_t)qi * 512 + kj * 8) = ov;
}

// ---------------------------------------------------------------------------
// Build pvT[bh][n=t*64+d][w2] = attn[b][8*w2+t+1][h*64+d]  (bf16)
// ---------------------------------------------------------------------------
__global__ __launch_bounds__(256) void pvt_build(const u16* attn, u16* pvT)
{
  const int bh = blockIdx.x;
  const int b = bh >> 3, h = bh & 7;
  const int w0 = blockIdx.y * 32;
  __shared__ u16 TL[448 * 40];
  const int tid = threadIdx.x;
#pragma unroll
  for (int it = 0; it < 8; ++it) {
    int L = it * 256 + tid;
    int dg = L & 7, r = L >> 3;
    int w2l = r >> 3, tt = r & 7;
    if (tt < 7) {
      int m = 8 * (w0 + w2l) + tt + 1;
      u16x8 v = *(const u16x8*)(attn + ((size_t)b * 4096 + m) * 512 + h * 64 + dg * 8);
#pragma unroll
      for (int e = 0; e < 8; ++e)
        TL[(tt * 64 + dg * 8 + e) * 40 + w2l] = v[e];
    }
  }
  __syncthreads();
#pragma unroll
  for (int it = 0; it < 7; ++it) {
    int L = it * 256 + tid;
    int n = L >> 2, seg = L & 3;
    u16x8 v = *(const u16x8*)(&TL[n * 40 + seg * 8]);
    *(u16x8*)(pvT + ((size_t)bh * 448 + n) * 512 + w0 + seg * 8) = v;
  }
}

// ---------------------------------------------------------------------------
// LayerNorm + exact GELU on window token 0 (bf16 in/out). One wave per row.
// ---------------------------------------------------------------------------
__global__ __launch_bounds__(64) void ln_gelu(
    const u16* attn, const float* g, const float* be, u16* wt)
{
  const int r = blockIdx.x;            // r = b*512 + w
  const int b = r >> 9, w = r & 511;
  const int t = threadIdx.x;
  const u16* x = attn + (((size_t)b * 4096) + (size_t)w * 8) * 512;

  u16x8 v = *(const u16x8*)(x + t * 8);
  float xv[8];
  float s1 = 0.f, s2 = 0.f;
#pragma unroll
  for (int e = 0; e < 8; ++e) {
    xv[e] = b2f(v[e]);
    s1 += xv[e]; s2 += xv[e] * xv[e];
  }
#pragma unroll
  for (int off = 1; off < 64; off <<= 1) {
    s1 += __shfl_xor(s1, off);
    s2 += __shfl_xor(s2, off);
  }
  const float mu  = s1 * (1.0f / 512.0f);
  const float var = s2 * (1.0f / 512.0f) - mu * mu;
  const float inv = 1.0f / sqrtf(var + EPS_);

  const int d0 = t * 8;
  float4 g0 = *reinterpret_cast<const float4*>(g + d0);
  float4 g1 = *reinterpret_cast<const float4*>(g + d0 + 4);
  float4 b0 = *reinterpret_cast<const float4*>(be + d0);
  float4 b1 = *reinterpret_cast<const float4*>(be + d0 + 4);
  float gv[8] = {g0.x, g0.y, g0.z, g0.w, g1.x, g1.y, g1.z, g1.w};
  float bvv[8] = {b0.x, b0.y, b0.z, b0.w, b1.x, b1.y, b1.z, b1.w};
  const float k2 = 0.70710678118654752f;
  u16x8 ov;
#pragma unroll
  for (int e = 0; e < 8; ++e) {
    float y = (xv[e] - mu) * inv * gv[e] + bvv[e];
    ov[e] = f2b(0.5f * y * (1.0f + erff(y * k2)));
  }
  *(u16x8*)(wt + (size_t)r * 512 + d0) = ov;
}

// ---------------------------------------------------------------------------
// expS[bh][wq][wk] = exp(SCALE * pq . pk) in bf16. fp32 inputs, 64x64 tiles.
// ---------------------------------------------------------------------------
__global__ __launch_bounds__(256) void qk_exp(
    const float* pq, const float* pk, u16* expS)
{
  const int bh = blockIdx.z;
  const int b = bh >> 3, h = bh & 7;
  const int wq0 = blockIdx.x * 64, wk0 = blockIdx.y * 64;
  const int tid = threadIdx.x;

  __shared__ float Aq[64][68];
  __shared__ float Bk[64][68];

#pragma unroll
  for (int l = 0; l < 4; ++l) {
    int L = tid + l * 256;
    int row = L >> 4, dv = L & 15;
    float4 a = *reinterpret_cast<const float4*>(pq + ((size_t)b * 512 + wq0 + row) * 512 + h * 64 + dv * 4);
    float4 c = *reinterpret_cast<const float4*>(pk + ((size_t)b * 512 + wk0 + row) * 512 + h * 64 + dv * 4);
    Aq[dv * 4 + 0][row] = a.x; Aq[dv * 4 + 1][row] = a.y;
    Aq[dv * 4 + 2][row] = a.z; Aq[dv * 4 + 3][row] = a.w;
    Bk[dv * 4 + 0][row] = c.x; Bk[dv * 4 + 1][row] = c.y;
    Bk[dv * 4 + 2][row] = c.z; Bk[dv * 4 + 3][row] = c.w;
  }
  __syncthreads();

  const int r0 = (tid >> 4) * 4, c0 = (tid & 15) * 4;
  float acc[4][4];
#pragma unroll
  for (int i = 0; i < 4; ++i)
#pragma unroll
    for (int j = 0; j < 4; ++j) acc[i][j] = 0.0f;

#pragma unroll
  for (int kk = 0; kk < 64; ++kk) {
    float4 a = *reinterpret_cast<const float4*>(&Aq[kk][r0]);
    float4 c = *reinterpret_cast<const float4*>(&Bk[kk][c0]);
    float av[4] = {a.x, a.y, a.z, a.w};
    float cv[4] = {c.x, c.y, c.z, c.w};
#pragma unroll
    for (int i = 0; i < 4; ++i)
#pragma unroll
      for (int j = 0; j < 4; ++j)
        acc[i][j] = fmaf(av[i], cv[j], acc[i][j]);
  }

#pragma unroll
  for (int i = 0; i < 4; ++i) {
    u16x4 o;
#pragma unroll
    for (int j = 0; j < 4; ++j) o[j] = f2b(expf(acc[i][j] * SCALE_));
    *(u16x4*)(expS + ((size_t)bh * 512 + wq0 + r0 + i) * 512 + wk0 + c0) = o;
  }
}

// ---------------------------------------------------------------------------
// rsinv[row] = 1 / sum_k expS[row][k]  (bf16 in), one wave per row.
// ---------------------------------------------------------------------------
__global__ __launch_bounds__(64) void rs_inv(const u16* expS, float* rsinv)
{
  const int row = blockIdx.x;
  const int t = threadIdx.x;
  u16x8 v = *(const u16x8*)(expS + (size_t)row * 512 + t * 8);
  float s = 0.f;
#pragma unroll
  for (int e = 0; e < 8; ++e) s += b2f(v[e]);
#pragma unroll
  for (int off = 1; off < 64; off <<= 1) s += __shfl_xor(s, off);
  if (t == 0) rsinv[row] = 1.0f / s;
}

// ---------------------------------------------------------------------------
// PV MFMA GEMM + rescale + residual:
// X2[b][wq*7+t][h*64+d] = (sum_w2 expS[bh][wq][w2] * pvT[bh][t*64+d][w2]) *
//                         rsinv[bh*512+wq]  +  attn[b][8wq+t+1][h*64+d]
// 128(wq) x 64(d) tile, t = blockIdx.y. 4 waves each 64x32 (4x2 frags).
// ---------------------------------------------------------------------------
__global__ __launch_bounds__(256) void pv_mfma(
    const u16* __restrict__ expS, const u16* __restrict__ pvT,
    const float* __restrict__ rsinv, const u16* __restrict__ attn,
    u16* __restrict__ X2)
{
  __shared__ u16 As[8192];   // 128 x 64
  __shared__ u16 Bs[4096];   // 64 x 64
  const int tid = threadIdx.x;
  const int lane = tid & 63, wid = tid >> 6;
  const int wr = wid >> 1, wc = wid & 1;
  const int l15 = lane & 15, lh = lane >> 4, l7 = lane & 7;
  const int bh = blockIdx.z, b = bh >> 3, h = bh & 7;
  const int m0 = blockIdx.x * 128;
  const int nt = blockIdx.y;           // t in [0,7)

  const f32x4 fz = {0.f, 0.f, 0.f, 0.f};
  f32x4 acc[4][2];
#pragma unroll
  for (int m = 0; m < 4; ++m)
#pragma unroll
    for (int n = 0; n < 2; ++n) acc[m][n] = fz;

  int aoff[2], boff[2];
#pragma unroll
  for (int kh = 0; kh < 2; ++kh) {
    int slot = ((kh * 4 + lh) ^ l7) << 4;
    aoff[kh] = (wr * 64 + l15) * 128 + slot;
    boff[kh] = (wc * 32 + l15) * 128 + slot;
  }

  for (int k0 = 0; k0 < 512; k0 += 64) {
    __syncthreads();
#pragma unroll
    for (int it = 0; it < 4; ++it) {
      int L = it * 256 + tid;
      int r = L >> 3, s = L & 7;
      int c = s ^ (r & 7);
      gload_lds16(expS + ((size_t)bh * 512 + m0 + r) * 512 + k0 + c * 8,
                  (char*)As + (it * 256 + wid * 64) * 16);
    }
#pragma unroll
    for (int it = 0; it < 2; ++it) {
      int L = it * 256 + tid;
      int r = L >> 3, s = L & 7;
      int c = s ^ (r & 7);
      gload_lds16(pvT + ((size_t)bh * 448 + nt * 64 + r) * 512 + k0 + c * 8,
                  (char*)Bs + (it * 256 + wid * 64) * 16);
    }
    __syncthreads();
#pragma unroll
    for (int kh = 0; kh < 2; ++kh) {
      bf16x8 af[4], bfr[2];
#pragma unroll
      for (int m = 0; m < 4; ++m)
        af[m] = *(const bf16x8*)((const char*)As + aoff[kh] + m * 2048);
#pragma unroll
      for (int n = 0; n < 2; ++n)
        bfr[n] = *(const bf16x8*)((const char*)Bs + boff[kh] + n * 2048);
#pragma unroll
      for (int m = 0; m < 4; ++m)
#pragma unroll
        for (int n = 0; n < 2; ++n)
          acc[m][n] = __builtin_amdgcn_mfma_f32_16x16x32_bf16(af[m], bfr[n], acc[m][n], 0, 0, 0);
    }
  }

#pragma unroll
  for (int m = 0; m < 4; ++m)
#pragma unroll
    for (int reg = 0; reg < 4; ++reg) {
      int gm = m0 + wr * 64 + m * 16 + lh * 4 + reg;      // wq
      float ri = rsinv[bh * 512 + gm];
#pragma unroll
      for (int n = 0; n < 2; ++n) {
        int d = wc * 32 + n * 16 + l15;
        float res = b2f(attn[((size_t)b * 4096 + gm * 8 + nt + 1) * 512 + h * 64 + d]);
        X2[((size_t)b * 3584 + gm * 7 + nt) * 512 + h * 64 + d] =
            f2b(acc[m][n][reg] * ri + res);
      }
    }
}

// ---------------------------------------------------------------------------
extern "C" void kernel_launch(void* const* d_in, const int* in_sizes, int n_in,
                              void* d_out, int out_size, void* d_ws, size_t ws_size,
                              hipStream_t stream)
{
  const float* k_in = (const float*)d_in[0];
  const float* v_in = (const float*)d_in[1];
  const float* q_in = (const float*)d_in[2];
  const float* Wk  = (const float*)d_in[4];
  const float* bk  = (const float*)d_in[5];
  const float* Wv  = (const float*)d_in[6];
  const float* bv  = (const float*)d_in[7];
  const float* Wq  = (const float*)d_in[8];
  const float* bq  = (const float*)d_in[9];
  const float* lng = (const float*)d_in[10];
  const float* lnb = (const float*)d_in[11];
  const float* Wpq = (const float*)d_in[12];
  const float* bpq = (const float*)d_in[13];
  const float* Wpk = (const float*)d_in[14];
  const float* bpk = (const float*)d_in[15];
  const float* Wo  = (const float*)d_in[16];
  const float* bo  = (const float*)d_in[17];
  float* out = (float*)d_out;

  char* ws = (char*)d_ws;
  const size_t MB = 1024 * 1024;
  u16* wtb  = (u16*)(ws);                 // 6 x 512KB transposed bf16 weights
  u16* k_bf = (u16*)(ws + 16 * MB);
  u16* v_bf = (u16*)(ws + 48 * MB);
  u16* q_bf = (u16*)(ws + 80 * MB);
  u16* kp   = (u16*)(ws + 112 * MB);
  u16* vp   = (u16*)(ws + 144 * MB);
  u16* qp0  = (u16*)(ws + 176 * MB);
  u16* attn = (u16*)(ws + 208 * MB);
  // phase 2 (k_bf..qp0 regions reused)
  u16*   wt    = (u16*)(ws + 16 * MB);    // 4MB
  float* pq    = (float*)(ws + 20 * MB);  // 8MB
  float* pk    = (float*)(ws + 28 * MB);  // 8MB
  float* rsinv = (float*)(ws + 36 * MB);  // 128KB
  u16*   expS  = (u16*)(ws + 40 * MB);    // 32MB
  u16*   pvT   = (u16*)(ws + 72 * MB);    // 28MB
  u16*   X2    = (u16*)(ws + 104 * MB);   // 28MB

  u16* Wkt  = wtb;
  u16* Wvt  = wtb + 1 * 262144;
  u16* Wqt  = wtb + 2 * 262144;
  u16* Wpqt = wtb + 3 * 262144;
  u16* Wpkt = wtb + 4 * 262144;
  u16* Wot  = wtb + 5 * 262144;

  wconv<<<dim3(8, 8, 6), 256, 0, stream>>>(Wk, Wv, Wq, Wpq, Wpk, Wo, wtb);
  inconv<<<dim3(8192, 1, 3), 256, 0, stream>>>(k_in, v_in, q_in, k_bf, v_bf, q_bf);

  gemm_bf16<<<dim3(256, 4), 256, 0, stream>>>(k_bf, Wkt, bk, kp, 0);
  gemm_bf16<<<dim3(256, 4), 256, 0, stream>>>(v_bf, Wvt, bv, vp, 0);
  gemm_bf16<<<dim3(256, 4), 256, 0, stream>>>(q_bf, Wqt, bq, qp0, 0);

  attn_win<<<dim3(8, 512, 8), 64, 0, stream>>>(kp, vp, qp0, attn);
  pvt_build<<<dim3(64, 16), 256, 0, stream>>>(attn, pvT);
  ln_gelu<<<4096, 64, 0, stream>>>(attn, lng, lnb, wt);

  gemm_bf16<<<dim3(32, 4), 256, 0, stream>>>(wt, Wpqt, bpq, pq, 1);
  gemm_bf16<<<dim3(32, 4), 256, 0, stream>>>(wt, Wpkt, bpk, pk, 1);

  qk_exp<<<dim3(8, 8, 64), 256, 0, stream>>>(pq, pk, expS);
  rs_inv<<<32768, 64, 0, stream>>>(expS, rsinv);
  pv_mfma<<<dim3(4, 7, 64), 256, 0, stream>>>(expS, pvT, rsinv, attn, X2);

  gemm_bf16<<<dim3(224, 4), 256, 0, stream>>>(X2, Wot, bo, out, 1);
}

// Round 3
// 343.038 us; speedup vs baseline: 3.4965x; 1.1210x over previous
//
#include <hip/hip_runtime.h>
#include <hip/hip_bf16.h>
#include <math.h>

#define SCALE_ 0.04419417382415922f   // 512^-0.5
#define EPS_  1e-5f

typedef unsigned short u16;
typedef __attribute__((ext_vector_type(8))) short     bf16x8;
typedef __attribute__((ext_vector_type(4))) float     f32x4;
typedef __attribute__((ext_vector_type(8))) unsigned short u16x8;
typedef __attribute__((ext_vector_type(4))) unsigned short u16x4;

__device__ __forceinline__ u16 f2b(float f) {
  union { float f; unsigned int u; } x; x.f = f;
  unsigned int u = x.u;
  return (u16)((u + 0x7FFFu + ((u >> 16) & 1u)) >> 16);
}
__device__ __forceinline__ float b2f(u16 h) {
  union { unsigned int u; float f; } x; x.u = ((unsigned int)h) << 16;
  return x.f;
}
__device__ __forceinline__ void gload_lds16(const void* g, void* l) {
  __builtin_amdgcn_global_load_lds(
      (const __attribute__((address_space(1))) void*)g,
      (__attribute__((address_space(3))) void*)l, 16, 0, 0);
}

// ---------------------------------------------------------------------------
// Weight convert+transpose: Wt[n][k] = bf16(W[k][n]), 512x512, z selects weight
// ---------------------------------------------------------------------------
__global__ __launch_bounds__(256) void wconv(
    const float* W0, const float* W1, const float* W2,
    const float* W3, const float* W4, const float* W5, u16* wt)
{
  const float* W;
  switch (blockIdx.z) {
    case 0: W = W0; break; case 1: W = W1; break; case 2: W = W2; break;
    case 3: W = W3; break; case 4: W = W4; break; default: W = W5; break;
  }
  u16* Wt = wt + (size_t)blockIdx.z * 262144;
  const int k0 = blockIdx.x * 64, n0 = blockIdx.y * 64;
  __shared__ float T[64][68];
  const int tid = threadIdx.x;
#pragma unroll
  for (int it = 0; it < 4; ++it) {
    int L = it * 256 + tid;
    int r = L >> 4, cg = L & 15;
    float4 v = *reinterpret_cast<const float4*>(W + (size_t)(k0 + r) * 512 + n0 + cg * 4);
    T[r][cg * 4 + 0] = v.x; T[r][cg * 4 + 1] = v.y;
    T[r][cg * 4 + 2] = v.z; T[r][cg * 4 + 3] = v.w;
  }
  __syncthreads();
#pragma unroll
  for (int it = 0; it < 2; ++it) {
    int L = it * 256 + tid;
    int rn = L >> 3, kg = L & 7;
    u16x8 o;
#pragma unroll
    for (int e = 0; e < 8; ++e) o[e] = f2b(T[kg * 8 + e][rn]);
    *(u16x8*)(Wt + (size_t)(n0 + rn) * 512 + k0 + kg * 8) = o;
  }
}

// ---------------------------------------------------------------------------
// Fused projection GEMM: C_bf16[M x 512] = bf16(A_f32) @ Bt^T + bias.
// A is fp32, converted during reg-staged LDS write. B staged via gload_lds.
// 128x128 tile, BK=64, 4 waves each 64x64. XOR-swizzled LDS. z selects set.
// ---------------------------------------------------------------------------
__global__ __launch_bounds__(256) void gemm_proj(
    const float* A0, const u16* Bt0, const float* bi0, u16* C0,
    const float* A1, const u16* Bt1, const float* bi1, u16* C1,
    const float* A2, const u16* Bt2, const float* bi2, u16* C2)
{
  const float *A, *bias; const u16* Bt; u16* C;
  if (blockIdx.z == 0)      { A = A0; Bt = Bt0; bias = bi0; C = C0; }
  else if (blockIdx.z == 1) { A = A1; Bt = Bt1; bias = bi1; C = C1; }
  else                      { A = A2; Bt = Bt2; bias = bi2; C = C2; }

  __shared__ u16 As[8192];   // 128 x 64
  __shared__ u16 Bs[8192];   // 128 x 64
  const int tid = threadIdx.x;
  const int lane = tid & 63, wid = tid >> 6;
  const int wr = wid >> 1, wc = wid & 1;
  const int l15 = lane & 15, lh = lane >> 4, l7 = lane & 7;
  const int m0 = blockIdx.x * 128, n0 = blockIdx.y * 128;

  const f32x4 fz = {0.f, 0.f, 0.f, 0.f};
  f32x4 acc[4][4];
#pragma unroll
  for (int m = 0; m < 4; ++m)
#pragma unroll
    for (int n = 0; n < 4; ++n) acc[m][n] = fz;

  int aoff[2], boff[2];
#pragma unroll
  for (int kh = 0; kh < 2; ++kh) {
    int slot = ((kh * 4 + lh) ^ l7) << 4;
    aoff[kh] = (wr * 64 + l15) * 128 + slot;
    boff[kh] = (wc * 64 + l15) * 128 + slot;
  }

  for (int k0 = 0; k0 < 512; k0 += 64) {
    __syncthreads();
    // B tile: async direct-to-LDS
#pragma unroll
    for (int it = 0; it < 4; ++it) {
      int L = it * 256 + tid;
      int r = L >> 3, s = L & 7;
      int c = s ^ (r & 7);
      gload_lds16(Bt + (size_t)(n0 + r) * 512 + k0 + c * 8,
                  (char*)Bs + (it * 256 + wid * 64) * 16);
    }
    // A tile: fp32 -> regs -> bf16 -> LDS (same swizzled layout)
    float4 xa[4], xb[4];
#pragma unroll
    for (int it = 0; it < 4; ++it) {
      int L = it * 256 + tid;
      int r = L >> 3, s = L & 7;
      int c = s ^ (r & 7);
      const float* ga = A + (size_t)(m0 + r) * 512 + k0 + c * 8;
      xa[it] = *reinterpret_cast<const float4*>(ga);
      xb[it] = *reinterpret_cast<const float4*>(ga + 4);
    }
#pragma unroll
    for (int it = 0; it < 4; ++it) {
      int L = it * 256 + tid;
      u16x8 o;
      o[0] = f2b(xa[it].x); o[1] = f2b(xa[it].y);
      o[2] = f2b(xa[it].z); o[3] = f2b(xa[it].w);
      o[4] = f2b(xb[it].x); o[5] = f2b(xb[it].y);
      o[6] = f2b(xb[it].z); o[7] = f2b(xb[it].w);
      *(u16x8*)((char*)As + L * 16) = o;
    }
    __syncthreads();
#pragma unroll
    for (int kh = 0; kh < 2; ++kh) {
      bf16x8 af[4], bfr[4];
#pragma unroll
      for (int m = 0; m < 4; ++m)
        af[m] = *(const bf16x8*)((const char*)As + aoff[kh] + m * 2048);
#pragma unroll
      for (int n = 0; n < 4; ++n)
        bfr[n] = *(const bf16x8*)((const char*)Bs + boff[kh] + n * 2048);
#pragma unroll
      for (int m = 0; m < 4; ++m)
#pragma unroll
        for (int n = 0; n < 4; ++n)
          acc[m][n] = __builtin_amdgcn_mfma_f32_16x16x32_bf16(af[m], bfr[n], acc[m][n], 0, 0, 0);
    }
  }

  const int gn0 = n0 + wc * 64 + l15;
  float bv[4];
#pragma unroll
  for (int n = 0; n < 4; ++n) bv[n] = bias[gn0 + n * 16];
#pragma unroll
  for (int m = 0; m < 4; ++m)
#pragma unroll
    for (int reg = 0; reg < 4; ++reg) {
      int gm = m0 + wr * 64 + m * 16 + lh * 4 + reg;
#pragma unroll
      for (int n = 0; n < 4; ++n)
        C[(size_t)gm * 512 + gn0 + n * 16] = f2b(acc[m][n][reg] + bv[n]);
    }
}

// ---------------------------------------------------------------------------
// bf16 MFMA GEMM: C[M x 512] = A[M x 512] @ Bt^T + bias.  Bt is [n][k].
// ---------------------------------------------------------------------------
__global__ __launch_bounds__(256) void gemm_bf16(
    const u16* __restrict__ A, const u16* __restrict__ Bt,
    const float* __restrict__ bias, void* __restrict__ Cout, int outf32)
{
  __shared__ u16 As[8192];   // 128 x 64
  __shared__ u16 Bs[8192];   // 128 x 64
  const int tid = threadIdx.x;
  const int lane = tid & 63, wid = tid >> 6;
  const int wr = wid >> 1, wc = wid & 1;
  const int l15 = lane & 15, lh = lane >> 4, l7 = lane & 7;
  const int m0 = blockIdx.x * 128, n0 = blockIdx.y * 128;

  const f32x4 fz = {0.f, 0.f, 0.f, 0.f};
  f32x4 acc[4][4];
#pragma unroll
  for (int m = 0; m < 4; ++m)
#pragma unroll
    for (int n = 0; n < 4; ++n) acc[m][n] = fz;

  int aoff[2], boff[2];
#pragma unroll
  for (int kh = 0; kh < 2; ++kh) {
    int slot = ((kh * 4 + lh) ^ l7) << 4;
    aoff[kh] = (wr * 64 + l15) * 128 + slot;
    boff[kh] = (wc * 64 + l15) * 128 + slot;
  }

  for (int k0 = 0; k0 < 512; k0 += 64) {
    __syncthreads();
#pragma unroll
    for (int it = 0; it < 4; ++it) {
      int L = it * 256 + tid;
      int r = L >> 3, s = L & 7;
      int c = s ^ (r & 7);
      const u16* ga = A  + (size_t)(m0 + r) * 512 + k0 + c * 8;
      const u16* gb = Bt + (size_t)(n0 + r) * 512 + k0 + c * 8;
      char* la = (char*)As + (it * 256 + wid * 64) * 16;
      char* lb = (char*)Bs + (it * 256 + wid * 64) * 16;
      gload_lds16(ga, la);
      gload_lds16(gb, lb);
    }
    __syncthreads();
#pragma unroll
    for (int kh = 0; kh < 2; ++kh) {
      bf16x8 af[4], bfr[4];
#pragma unroll
      for (int m = 0; m < 4; ++m)
        af[m] = *(const bf16x8*)((const char*)As + aoff[kh] + m * 2048);
#pragma unroll
      for (int n = 0; n < 4; ++n)
        bfr[n] = *(const bf16x8*)((const char*)Bs + boff[kh] + n * 2048);
#pragma unroll
      for (int m = 0; m < 4; ++m)
#pragma unroll
        for (int n = 0; n < 4; ++n)
          acc[m][n] = __builtin_amdgcn_mfma_f32_16x16x32_bf16(af[m], bfr[n], acc[m][n], 0, 0, 0);
    }
  }

  const int gn0 = n0 + wc * 64 + l15;
  float bv[4];
#pragma unroll
  for (int n = 0; n < 4; ++n) bv[n] = bias[gn0 + n * 16];

  if (outf32) {
    float* C = (float*)Cout;
#pragma unroll
    for (int m = 0; m < 4; ++m)
#pragma unroll
      for (int reg = 0; reg < 4; ++reg) {
        int gm = m0 + wr * 64 + m * 16 + lh * 4 + reg;
#pragma unroll
        for (int n = 0; n < 4; ++n)
          C[(size_t)gm * 512 + gn0 + n * 16] = acc[m][n][reg] + bv[n];
      }
  } else {
    u16* C = (u16*)Cout;
#pragma unroll
    for (int m = 0; m < 4; ++m)
#pragma unroll
      for (int reg = 0; reg < 4; ++reg) {
        int gm = m0 + wr * 64 + m * 16 + lh * 4 + reg;
#pragma unroll
        for (int n = 0; n < 4; ++n)
          C[(size_t)gm * 512 + gn0 + n * 16] = f2b(acc[m][n][reg] + bv[n]);
      }
  }
}

// ---------------------------------------------------------------------------
// Window attention (bf16 in/out), fused q 5-tap smoothing. fp32 math.
// ---------------------------------------------------------------------------
__global__ __launch_bounds__(64) void attn_win(
    const u16* kp, const u16* vp, const u16* qp0, u16* attn)
{
  const int h = blockIdx.x, w = blockIdx.y, b = blockIdx.z;
  const int t = threadIdx.x;
  __shared__ float ks[8][68], vs[8][68], qr[12][68], qs[8][68], Ps[8][9];
  const size_t base = ((size_t)b * 4096 + (size_t)w * 8) * 512 + h * 64;

  {
    int i = t >> 3, dg = t & 7;
    u16x8 kv = *(const u16x8*)(kp + base + (size_t)i * 512 + dg * 8);
    u16x8 vv = *(const u16x8*)(vp + base + (size_t)i * 512 + dg * 8);
#pragma unroll
    for (int e = 0; e < 8; ++e) {
      ks[i][dg * 8 + e] = b2f(kv[e]);
      vs[i][dg * 8 + e] = b2f(vv[e]);
    }
  }
#pragma unroll
  for (int l = 0; l < 2; ++l) {
    int L = t + l * 64;
    if (L < 96) {
      int i = L >> 3, dg = L & 7;
      int m = w * 8 - 2 + i;
      if (m >= 0 && m < 4096) {
        u16x8 qv = *(const u16x8*)(qp0 + ((size_t)b * 4096 + m) * 512 + h * 64 + dg * 8);
#pragma unroll
        for (int e = 0; e < 8; ++e) qr[i][dg * 8 + e] = b2f(qv[e]);
      } else {
#pragma unroll
        for (int e = 0; e < 8; ++e) qr[i][dg * 8 + e] = 0.0f;
      }
    }
  }
  __syncthreads();
#pragma unroll
  for (int j = 0; j < 8; ++j)
    qs[j][t] = 0.2f * (qr[j][t] + qr[j + 1][t] + qr[j + 2][t] + qr[j + 3][t] + qr[j + 4][t]);
  __syncthreads();

  const int qi = t >> 3, kj = t & 7;
  float s = 0.0f;
#pragma unroll
  for (int d = 0; d < 64; ++d) s = fmaf(qs[qi][d], ks[kj][d], s);
  s *= SCALE_;
  float mx = s;
  mx = fmaxf(mx, __shfl_xor(mx, 1));
  mx = fmaxf(mx, __shfl_xor(mx, 2));
  mx = fmaxf(mx, __shfl_xor(mx, 4));
  float e = expf(s - mx);
  float sum = e;
  sum += __shfl_xor(sum, 1);
  sum += __shfl_xor(sum, 2);
  sum += __shfl_xor(sum, 4);
  Ps[qi][kj] = e / sum;
  __syncthreads();

  float o[8];
#pragma unroll
  for (int c = 0; c < 8; ++c) o[c] = 0.0f;
#pragma unroll
  for (int tt = 0; tt < 8; ++tt) {
    float pw = Ps[qi][tt];
#pragma unroll
    for (int c = 0; c < 8; ++c) o[c] = fmaf(pw, vs[tt][kj * 8 + c], o[c]);
  }
  u16x8 ov;
#pragma unroll
  for (int c = 0; c < 8; ++c) ov[c] = f2b(o[c]);
  *(u16x8*)(attn + base + (size_t)qi * 512 + kj * 8) = ov;
}

// ---------------------------------------------------------------------------
// Build pvT[bh][n=t*64+d][w2] = attn[b][8*w2+t+1][h*64+d]  (bf16)
// ---------------------------------------------------------------------------
__global__ __launch_bounds__(256) void pvt_build(const u16* attn, u16* pvT)
{
  const int bh = blockIdx.x;
  const int b = bh >> 3, h = bh & 7;
  const int w0 = blockIdx.y * 32;
  __shared__ u16 TL[448 * 40];
  const int tid = threadIdx.x;
#pragma unroll
  for (int it = 0; it < 8; ++it) {
    int L = it * 256 + tid;
    int dg = L & 7, r = L >> 3;
    int w2l = r >> 3, tt = r & 7;
    if (tt < 7) {
      int m = 8 * (w0 + w2l) + tt + 1;
      u16x8 v = *(const u16x8*)(attn + ((size_t)b * 4096 + m) * 512 + h * 64 + dg * 8);
#pragma unroll
      for (int e = 0; e < 8; ++e)
        TL[(tt * 64 + dg * 8 + e) * 40 + w2l] = v[e];
    }
  }
  __syncthreads();
#pragma unroll
  for (int it = 0; it < 7; ++it) {
    int L = it * 256 + tid;
    int n = L >> 2, seg = L & 3;
    u16x8 v = *(const u16x8*)(&TL[n * 40 + seg * 8]);
    *(u16x8*)(pvT + ((size_t)bh * 448 + n) * 512 + w0 + seg * 8) = v;
  }
}

// ---------------------------------------------------------------------------
// LayerNorm + exact GELU on window token 0 (bf16 in/out). One wave per row.
// ---------------------------------------------------------------------------
__global__ __launch_bounds__(64) void ln_gelu(
    const u16* attn, const float* g, const float* be, u16* wt)
{
  const int r = blockIdx.x;            // r = b*512 + w
  const int b = r >> 9, w = r & 511;
  const int t = threadIdx.x;
  const u16* x = attn + (((size_t)b * 4096) + (size_t)w * 8) * 512;

  u16x8 v = *(const u16x8*)(x + t * 8);
  float xv[8];
  float s1 = 0.f, s2 = 0.f;
#pragma unroll
  for (int e = 0; e < 8; ++e) {
    xv[e] = b2f(v[e]);
    s1 += xv[e]; s2 += xv[e] * xv[e];
  }
#pragma unroll
  for (int off = 1; off < 64; off <<= 1) {
    s1 += __shfl_xor(s1, off);
    s2 += __shfl_xor(s2, off);
  }
  const float mu  = s1 * (1.0f / 512.0f);
  const float var = s2 * (1.0f / 512.0f) - mu * mu;
  const float inv = 1.0f / sqrtf(var + EPS_);

  const int d0 = t * 8;
  float4 g0 = *reinterpret_cast<const float4*>(g + d0);
  float4 g1 = *reinterpret_cast<const float4*>(g + d0 + 4);
  float4 b0 = *reinterpret_cast<const float4*>(be + d0);
  float4 b1 = *reinterpret_cast<const float4*>(be + d0 + 4);
  float gv[8] = {g0.x, g0.y, g0.z, g0.w, g1.x, g1.y, g1.z, g1.w};
  float bvv[8] = {b0.x, b0.y, b0.z, b0.w, b1.x, b1.y, b1.z, b1.w};
  const float k2 = 0.70710678118654752f;
  u16x8 ov;
#pragma unroll
  for (int e = 0; e < 8; ++e) {
    float y = (xv[e] - mu) * inv * gv[e] + bvv[e];
    ov[e] = f2b(0.5f * y * (1.0f + erff(y * k2)));
  }
  *(u16x8*)(wt + (size_t)r * 512 + d0) = ov;
}

// ---------------------------------------------------------------------------
// expS[bh][wq][wk] = exp(SCALE * pq . pk) in bf16. fp32 inputs, 64x64 tiles.
// ---------------------------------------------------------------------------
__global__ __launch_bounds__(256) void qk_exp(
    const float* pq, const float* pk, u16* expS)
{
  const int bh = blockIdx.z;
  const int b = bh >> 3, h = bh & 7;
  const int wq0 = blockIdx.x * 64, wk0 = blockIdx.y * 64;
  const int tid = threadIdx.x;

  __shared__ float Aq[64][68];
  __shared__ float Bk[64][68];

#pragma unroll
  for (int l = 0; l < 4; ++l) {
    int L = tid + l * 256;
    int row = L >> 4, dv = L & 15;
    float4 a = *reinterpret_cast<const float4*>(pq + ((size_t)b * 512 + wq0 + row) * 512 + h * 64 + dv * 4);
    float4 c = *reinterpret_cast<const float4*>(pk + ((size_t)b * 512 + wk0 + row) * 512 + h * 64 + dv * 4);
    Aq[dv * 4 + 0][row] = a.x; Aq[dv * 4 + 1][row] = a.y;
    Aq[dv * 4 + 2][row] = a.z; Aq[dv * 4 + 3][row] = a.w;
    Bk[dv * 4 + 0][row] = c.x; Bk[dv * 4 + 1][row] = c.y;
    Bk[dv * 4 + 2][row] = c.z; Bk[dv * 4 + 3][row] = c.w;
  }
  __syncthreads();

  const int r0 = (tid >> 4) * 4, c0 = (tid & 15) * 4;
  float acc[4][4];
#pragma unroll
  for (int i = 0; i < 4; ++i)
#pragma unroll
    for (int j = 0; j < 4; ++j) acc[i][j] = 0.0f;

#pragma unroll
  for (int kk = 0; kk < 64; ++kk) {
    float4 a = *reinterpret_cast<const float4*>(&Aq[kk][r0]);
    float4 c = *reinterpret_cast<const float4*>(&Bk[kk][c0]);
    float av[4] = {a.x, a.y, a.z, a.w};
    float cv[4] = {c.x, c.y, c.z, c.w};
#pragma unroll
    for (int i = 0; i < 4; ++i)
#pragma unroll
      for (int j = 0; j < 4; ++j)
        acc[i][j] = fmaf(av[i], cv[j], acc[i][j]);
  }

#pragma unroll
  for (int i = 0; i < 4; ++i) {
    u16x4 o;
#pragma unroll
    for (int j = 0; j < 4; ++j) o[j] = f2b(expf(acc[i][j] * SCALE_));
    *(u16x4*)(expS + ((size_t)bh * 512 + wq0 + r0 + i) * 512 + wk0 + c0) = o;
  }
}

// ---------------------------------------------------------------------------
// rsinv[row] = 1 / sum_k expS[row][k]  (bf16 in). 4 rows per 256-thread block.
// ---------------------------------------------------------------------------
__global__ __launch_bounds__(256) void rs_inv(const u16* expS, float* rsinv)
{
  const int row = blockIdx.x * 4 + (threadIdx.x >> 6);
  const int t = threadIdx.x & 63;
  u16x8 v = *(const u16x8*)(expS + (size_t)row * 512 + t * 8);
  float s = 0.f;
#pragma unroll
  for (int e = 0; e < 8; ++e) s += b2f(v[e]);
#pragma unroll
  for (int off = 1; off < 64; off <<= 1) s += __shfl_xor(s, off);
  if (t == 0) rsinv[row] = 1.0f / s;
}

// ---------------------------------------------------------------------------
// PV MFMA GEMM + rescale + residual:
// X2[b][wq*7+t][h*64+d] = (sum_w2 expS[bh][wq][w2] * pvT[bh][t*64+d][w2]) *
//                         rsinv[bh*512+wq]  +  attn[b][8wq+t+1][h*64+d]
// ---------------------------------------------------------------------------
__global__ __launch_bounds__(256) void pv_mfma(
    const u16* __restrict__ expS, const u16* __restrict__ pvT,
    const float* __restrict__ rsinv, const u16* __restrict__ attn,
    u16* __restrict__ X2)
{
  __shared__ u16 As[8192];   // 128 x 64
  __shared__ u16 Bs[4096];   // 64 x 64
  const int tid = threadIdx.x;
  const int lane = tid & 63, wid = tid >> 6;
  const int wr = wid >> 1, wc = wid & 1;
  const int l15 = lane & 15, lh = lane >> 4, l7 = lane & 7;
  const int bh = blockIdx.z, b = bh >> 3, h = bh & 7;
  const int m0 = blockIdx.x * 128;
  const int nt = blockIdx.y;           // t in [0,7)

  const f32x4 fz = {0.f, 0.f, 0.f, 0.f};
  f32x4 acc[4][2];
#pragma unroll
  for (int m = 0; m < 4; ++m)
#pragma unroll
    for (int n = 0; n < 2; ++n) acc[m][n] = fz;

  int aoff[2], boff[2];
#pragma unroll
  for (int kh = 0; kh < 2; ++kh) {
    int slot = ((kh * 4 + lh) ^ l7) << 4;
    aoff[kh] = (wr * 64 + l15) * 128 + slot;
    boff[kh] = (wc * 32 + l15) * 128 + slot;
  }

  for (int k0 = 0; k0 < 512; k0 += 64) {
    __syncthreads();
#pragma unroll
    for (int it = 0; it < 4; ++it) {
      int L = it * 256 + tid;
      int r = L >> 3, s = L & 7;
      int c = s ^ (r & 7);
      gload_lds16(expS + ((size_t)bh * 512 + m0 + r) * 512 + k0 + c * 8,
                  (char*)As + (it * 256 + wid * 64) * 16);
    }
#pragma unroll
    for (int it = 0; it < 2; ++it) {
      int L = it * 256 + tid;
      int r = L >> 3, s = L & 7;
      int c = s ^ (r & 7);
      gload_lds16(pvT + ((size_t)bh * 448 + nt * 64 + r) * 512 + k0 + c * 8,
                  (char*)Bs + (it * 256 + wid * 64) * 16);
    }
    __syncthreads();
#pragma unroll
    for (int kh = 0; kh < 2; ++kh) {
      bf16x8 af[4], bfr[2];
#pragma unroll
      for (int m = 0; m < 4; ++m)
        af[m] = *(const bf16x8*)((const char*)As + aoff[kh] + m * 2048);
#pragma unroll
      for (int n = 0; n < 2; ++n)
        bfr[n] = *(const bf16x8*)((const char*)Bs + boff[kh] + n * 2048);
#pragma unroll
      for (int m = 0; m < 4; ++m)
#pragma unroll
        for (int n = 0; n < 2; ++n)
          acc[m][n] = __builtin_amdgcn_mfma_f32_16x16x32_bf16(af[m], bfr[n], acc[m][n], 0, 0, 0);
    }
  }

#pragma unroll
  for (int m = 0; m < 4; ++m)
#pragma unroll
    for (int reg = 0; reg < 4; ++reg) {
      int gm = m0 + wr * 64 + m * 16 + lh * 4 + reg;      // wq
      float ri = rsinv[bh * 512 + gm];
#pragma unroll
      for (int n = 0; n < 2; ++n) {
        int d = wc * 32 + n * 16 + l15;
        float res = b2f(attn[((size_t)b * 4096 + gm * 8 + nt + 1) * 512 + h * 64 + d]);
        X2[((size_t)b * 3584 + gm * 7 + nt) * 512 + h * 64 + d] =
            f2b(acc[m][n][reg] * ri + res);
      }
    }
}

// ---------------------------------------------------------------------------
extern "C" void kernel_launch(void* const* d_in, const int* in_sizes, int n_in,
                              void* d_out, int out_size, void* d_ws, size_t ws_size,
                              hipStream_t stream)
{
  const float* k_in = (const float*)d_in[0];
  const float* v_in = (const float*)d_in[1];
  const float* q_in = (const float*)d_in[2];
  const float* Wk  = (const float*)d_in[4];
  const float* bk  = (const float*)d_in[5];
  const float* Wv  = (const float*)d_in[6];
  const float* bv  = (const float*)d_in[7];
  const float* Wq  = (const float*)d_in[8];
  const float* bq  = (const float*)d_in[9];
  const float* lng = (const float*)d_in[10];
  const float* lnb = (const float*)d_in[11];
  const float* Wpq = (const float*)d_in[12];
  const float* bpq = (const float*)d_in[13];
  const float* Wpk = (const float*)d_in[14];
  const float* bpk = (const float*)d_in[15];
  const float* Wo  = (const float*)d_in[16];
  const float* bo  = (const float*)d_in[17];
  float* out = (float*)d_out;

  char* ws = (char*)d_ws;
  const size_t MB = 1024 * 1024;
  u16* wtb  = (u16*)(ws);                 // 6 x 512KB transposed bf16 weights
  u16* kp   = (u16*)(ws + 16 * MB);       // 34MB
  u16* vp   = (u16*)(ws + 52 * MB);       // 34MB
  u16* qp0  = (u16*)(ws + 88 * MB);       // 34MB
  u16* attn = (u16*)(ws + 124 * MB);      // 34MB
  // phase 2 (kp/vp/qp0 regions reused after attn_win)
  u16*   wt    = (u16*)(ws + 16 * MB);    // 4MB
  float* pq    = (float*)(ws + 20 * MB);  // 8MB
  float* pk    = (float*)(ws + 28 * MB);  // 8MB
  float* rsinv = (float*)(ws + 36 * MB);  // 128KB
  u16*   expS  = (u16*)(ws + 40 * MB);    // 34MB
  u16*   pvT   = (u16*)(ws + 76 * MB);    // 30MB
  u16*   X2    = (u16*)(ws + 160 * MB);   // 30MB

  u16* Wkt  = wtb;
  u16* Wvt  = wtb + 1 * 262144;
  u16* Wqt  = wtb + 2 * 262144;
  u16* Wpqt = wtb + 3 * 262144;
  u16* Wpkt = wtb + 4 * 262144;
  u16* Wot  = wtb + 5 * 262144;

  wconv<<<dim3(8, 8, 6), 256, 0, stream>>>(Wk, Wv, Wq, Wpq, Wpk, Wo, wtb);

  // fused fp32->bf16 + projection GEMMs (k, v, q in one dispatch)
  gemm_proj<<<dim3(256, 4, 3), 256, 0, stream>>>(
      k_in, Wkt, bk, kp,
      v_in, Wvt, bv, vp,
      q_in, Wqt, bq, qp0);

  attn_win<<<dim3(8, 512, 8), 64, 0, stream>>>(kp, vp, qp0, attn);
  pvt_build<<<dim3(64, 16), 256, 0, stream>>>(attn, pvT);
  ln_gelu<<<4096, 64, 0, stream>>>(attn, lng, lnb, wt);

  gemm_bf16<<<dim3(32, 4), 256, 0, stream>>>(wt, Wpqt, bpq, pq, 1);
  gemm_bf16<<<dim3(32, 4), 256, 0, stream>>>(wt, Wpkt, bpk, pk, 1);

  qk_exp<<<dim3(8, 8, 64), 256, 0, stream>>>(pq, pk, expS);
  rs_inv<<<8192, 256, 0, stream>>>(expS, rsinv);
  pv_mfma<<<dim3(4, 7, 64), 256, 0, stream>>>(expS, pvT, rsinv, attn, X2);

  gemm_bf16<<<dim3(224, 4), 256, 0, stream>>>(X2, Wot, bo, out, 1);
}

// Round 4
// 301.254 us; speedup vs baseline: 3.9814x; 1.1387x over previous
//
#include <hip/hip_runtime.h>
#include <hip/hip_bf16.h>
#include <math.h>

#define SCALE_ 0.04419417382415922f   // 512^-0.5
#define EPS_  1e-5f

typedef unsigned short u16;
typedef __attribute__((ext_vector_type(8))) short     bf16x8;
typedef __attribute__((ext_vector_type(4))) float     f32x4;
typedef __attribute__((ext_vector_type(8))) unsigned short u16x8;
typedef __attribute__((ext_vector_type(4))) unsigned short u16x4;

__device__ __forceinline__ u16 f2b(float f) {
  union { float f; unsigned int u; } x; x.f = f;
  unsigned int u = x.u;
  return (u16)((u + 0x7FFFu + ((u >> 16) & 1u)) >> 16);
}
__device__ __forceinline__ float b2f(u16 h) {
  union { unsigned int u; float f; } x; x.u = ((unsigned int)h) << 16;
  return x.f;
}
__device__ __forceinline__ void gload_lds16(const void* g, void* l) {
  __builtin_amdgcn_global_load_lds(
      (const __attribute__((address_space(1))) void*)g,
      (__attribute__((address_space(3))) void*)l, 16, 0, 0);
}

// ---------------------------------------------------------------------------
// Weight convert+transpose: Wt[n][k] = bf16(W[k][n]), 512x512, z selects weight
// ---------------------------------------------------------------------------
__global__ __launch_bounds__(256) void wconv(
    const float* W0, const float* W1, const float* W2,
    const float* W3, const float* W4, const float* W5, u16* wt)
{
  const float* W;
  switch (blockIdx.z) {
    case 0: W = W0; break; case 1: W = W1; break; case 2: W = W2; break;
    case 3: W = W3; break; case 4: W = W4; break; default: W = W5; break;
  }
  u16* Wt = wt + (size_t)blockIdx.z * 262144;
  const int k0 = blockIdx.x * 64, n0 = blockIdx.y * 64;
  __shared__ float T[64][68];
  const int tid = threadIdx.x;
#pragma unroll
  for (int it = 0; it < 4; ++it) {
    int L = it * 256 + tid;
    int r = L >> 4, cg = L & 15;
    float4 v = *reinterpret_cast<const float4*>(W + (size_t)(k0 + r) * 512 + n0 + cg * 4);
    T[r][cg * 4 + 0] = v.x; T[r][cg * 4 + 1] = v.y;
    T[r][cg * 4 + 2] = v.z; T[r][cg * 4 + 3] = v.w;
  }
  __syncthreads();
#pragma unroll
  for (int it = 0; it < 2; ++it) {
    int L = it * 256 + tid;
    int rn = L >> 3, kg = L & 7;
    u16x8 o;
#pragma unroll
    for (int e = 0; e < 8; ++e) o[e] = f2b(T[kg * 8 + e][rn]);
    *(u16x8*)(Wt + (size_t)(n0 + rn) * 512 + k0 + kg * 8) = o;
  }
}

// ---------------------------------------------------------------------------
// Strip projection GEMM: C_bf16[128 x 512 strip] = bf16(A_f32) @ Bt^T + bias.
// Full-N strip: A read+converted ONCE. 512 threads = 8 waves (2M x 4N),
// each wave 64x128. LDS: As 16KB + Bs 64KB, XOR-swizzled. z selects set.
// ---------------------------------------------------------------------------
__global__ __launch_bounds__(512) void gemm_proj(
    const float* A0, const u16* Bt0, const float* bi0, u16* C0,
    const float* A1, const u16* Bt1, const float* bi1, u16* C1,
    const float* A2, const u16* Bt2, const float* bi2, u16* C2)
{
  const float *A, *bias; const u16* Bt; u16* C;
  if (blockIdx.z == 0)      { A = A0; Bt = Bt0; bias = bi0; C = C0; }
  else if (blockIdx.z == 1) { A = A1; Bt = Bt1; bias = bi1; C = C1; }
  else                      { A = A2; Bt = Bt2; bias = bi2; C = C2; }

  __shared__ u16 As[8192];    // 128 rows x 64 k
  __shared__ u16 Bs[32768];   // 512 n-rows x 64 k
  const int tid = threadIdx.x;
  const int lane = tid & 63, wid = tid >> 6;
  const int wr = wid >> 2, wcn = wid & 3;          // 2 x 4 wave grid
  const int l15 = lane & 15, lh = lane >> 4, l7 = lane & 7;
  const int m0 = blockIdx.x * 128;

  const f32x4 fz = {0.f, 0.f, 0.f, 0.f};
  f32x4 acc[4][8];
#pragma unroll
  for (int m = 0; m < 4; ++m)
#pragma unroll
    for (int n = 0; n < 8; ++n) acc[m][n] = fz;

  int aoff[2], boff[2];
#pragma unroll
  for (int kh = 0; kh < 2; ++kh) {
    int slot = ((kh * 4 + lh) ^ l7) << 4;
    aoff[kh] = (wr * 64 + l15) * 128 + slot;
    boff[kh] = (wcn * 128 + l15) * 128 + slot;
  }

  for (int k0 = 0; k0 < 512; k0 += 64) {
    __syncthreads();
    // B panel (64k x 512n): async direct-to-LDS, 8 iters
#pragma unroll
    for (int it = 0; it < 8; ++it) {
      int L = it * 512 + tid;
      int r = L >> 3, s = L & 7;
      int c = s ^ (r & 7);
      gload_lds16(Bt + (size_t)r * 512 + k0 + c * 8,
                  (char*)Bs + (it * 512 + wid * 64) * 16);
    }
    // A tile (128 x 64): fp32 -> regs -> bf16 -> LDS, 2 iters
    float4 xa[2], xb[2];
#pragma unroll
    for (int it = 0; it < 2; ++it) {
      int L = it * 512 + tid;
      int r = L >> 3, s = L & 7;
      int c = s ^ (r & 7);
      const float* ga = A + (size_t)(m0 + r) * 512 + k0 + c * 8;
      xa[it] = *reinterpret_cast<const float4*>(ga);
      xb[it] = *reinterpret_cast<const float4*>(ga + 4);
    }
#pragma unroll
    for (int it = 0; it < 2; ++it) {
      int L = it * 512 + tid;
      u16x8 o;
      o[0] = f2b(xa[it].x); o[1] = f2b(xa[it].y);
      o[2] = f2b(xa[it].z); o[3] = f2b(xa[it].w);
      o[4] = f2b(xb[it].x); o[5] = f2b(xb[it].y);
      o[6] = f2b(xb[it].z); o[7] = f2b(xb[it].w);
      *(u16x8*)((char*)As + L * 16) = o;
    }
    __syncthreads();
#pragma unroll
    for (int kh = 0; kh < 2; ++kh) {
      bf16x8 af[4], bfr[8];
#pragma unroll
      for (int m = 0; m < 4; ++m)
        af[m] = *(const bf16x8*)((const char*)As + aoff[kh] + m * 2048);
#pragma unroll
      for (int n = 0; n < 8; ++n)
        bfr[n] = *(const bf16x8*)((const char*)Bs + boff[kh] + n * 2048);
#pragma unroll
      for (int m = 0; m < 4; ++m)
#pragma unroll
        for (int n = 0; n < 8; ++n)
          acc[m][n] = __builtin_amdgcn_mfma_f32_16x16x32_bf16(af[m], bfr[n], acc[m][n], 0, 0, 0);
    }
  }

  const int gn0 = wcn * 128 + l15;
  float bv[8];
#pragma unroll
  for (int n = 0; n < 8; ++n) bv[n] = bias[gn0 + n * 16];
#pragma unroll
  for (int m = 0; m < 4; ++m)
#pragma unroll
    for (int reg = 0; reg < 4; ++reg) {
      int gm = m0 + wr * 64 + m * 16 + lh * 4 + reg;
#pragma unroll
      for (int n = 0; n < 8; ++n)
        C[(size_t)gm * 512 + gn0 + n * 16] = f2b(acc[m][n][reg] + bv[n]);
    }
}

// ---------------------------------------------------------------------------
// Strip output GEMM: out_f32[128 x 512 strip] = A_bf16 @ Bt^T + bias.
// Same structure, A staged via gload_lds (already bf16).
// ---------------------------------------------------------------------------
__global__ __launch_bounds__(512) void gemm_out(
    const u16* __restrict__ A, const u16* __restrict__ Bt,
    const float* __restrict__ bias, float* __restrict__ C)
{
  __shared__ u16 As[8192];    // 128 x 64
  __shared__ u16 Bs[32768];   // 512 x 64
  const int tid = threadIdx.x;
  const int lane = tid & 63, wid = tid >> 6;
  const int wr = wid >> 2, wcn = wid & 3;
  const int l15 = lane & 15, lh = lane >> 4, l7 = lane & 7;
  const int m0 = blockIdx.x * 128;

  const f32x4 fz = {0.f, 0.f, 0.f, 0.f};
  f32x4 acc[4][8];
#pragma unroll
  for (int m = 0; m < 4; ++m)
#pragma unroll
    for (int n = 0; n < 8; ++n) acc[m][n] = fz;

  int aoff[2], boff[2];
#pragma unroll
  for (int kh = 0; kh < 2; ++kh) {
    int slot = ((kh * 4 + lh) ^ l7) << 4;
    aoff[kh] = (wr * 64 + l15) * 128 + slot;
    boff[kh] = (wcn * 128 + l15) * 128 + slot;
  }

  for (int k0 = 0; k0 < 512; k0 += 64) {
    __syncthreads();
#pragma unroll
    for (int it = 0; it < 8; ++it) {
      int L = it * 512 + tid;
      int r = L >> 3, s = L & 7;
      int c = s ^ (r & 7);
      gload_lds16(Bt + (size_t)r * 512 + k0 + c * 8,
                  (char*)Bs + (it * 512 + wid * 64) * 16);
    }
#pragma unroll
    for (int it = 0; it < 2; ++it) {
      int L = it * 512 + tid;
      int r = L >> 3, s = L & 7;
      int c = s ^ (r & 7);
      gload_lds16(A + (size_t)(m0 + r) * 512 + k0 + c * 8,
                  (char*)As + (it * 512 + wid * 64) * 16);
    }
    __syncthreads();
#pragma unroll
    for (int kh = 0; kh < 2; ++kh) {
      bf16x8 af[4], bfr[8];
#pragma unroll
      for (int m = 0; m < 4; ++m)
        af[m] = *(const bf16x8*)((const char*)As + aoff[kh] + m * 2048);
#pragma unroll
      for (int n = 0; n < 8; ++n)
        bfr[n] = *(const bf16x8*)((const char*)Bs + boff[kh] + n * 2048);
#pragma unroll
      for (int m = 0; m < 4; ++m)
#pragma unroll
        for (int n = 0; n < 8; ++n)
          acc[m][n] = __builtin_amdgcn_mfma_f32_16x16x32_bf16(af[m], bfr[n], acc[m][n], 0, 0, 0);
    }
  }

  const int gn0 = wcn * 128 + l15;
  float bv[8];
#pragma unroll
  for (int n = 0; n < 8; ++n) bv[n] = bias[gn0 + n * 16];
#pragma unroll
  for (int m = 0; m < 4; ++m)
#pragma unroll
    for (int reg = 0; reg < 4; ++reg) {
      int gm = m0 + wr * 64 + m * 16 + lh * 4 + reg;
#pragma unroll
      for (int n = 0; n < 8; ++n)
        C[(size_t)gm * 512 + gn0 + n * 16] = acc[m][n][reg] + bv[n];
    }
}

// ---------------------------------------------------------------------------
// pq/pk GEMM (small, f32 out): 128x128 tiles, z selects set. Bt is [n][k].
// ---------------------------------------------------------------------------
__global__ __launch_bounds__(256) void gemm_pp(
    const u16* __restrict__ A,
    const u16* __restrict__ Bt0, const float* __restrict__ bi0, float* __restrict__ C0,
    const u16* __restrict__ Bt1, const float* __restrict__ bi1, float* __restrict__ C1)
{
  const u16* Bt; const float* bias; float* C;
  if (blockIdx.z == 0) { Bt = Bt0; bias = bi0; C = C0; }
  else                 { Bt = Bt1; bias = bi1; C = C1; }

  __shared__ u16 As[8192];   // 128 x 64
  __shared__ u16 Bs[8192];   // 128 x 64
  const int tid = threadIdx.x;
  const int lane = tid & 63, wid = tid >> 6;
  const int wr = wid >> 1, wc = wid & 1;
  const int l15 = lane & 15, lh = lane >> 4, l7 = lane & 7;
  const int m0 = blockIdx.x * 128, n0 = blockIdx.y * 128;

  const f32x4 fz = {0.f, 0.f, 0.f, 0.f};
  f32x4 acc[4][4];
#pragma unroll
  for (int m = 0; m < 4; ++m)
#pragma unroll
    for (int n = 0; n < 4; ++n) acc[m][n] = fz;

  int aoff[2], boff[2];
#pragma unroll
  for (int kh = 0; kh < 2; ++kh) {
    int slot = ((kh * 4 + lh) ^ l7) << 4;
    aoff[kh] = (wr * 64 + l15) * 128 + slot;
    boff[kh] = (wc * 64 + l15) * 128 + slot;
  }

  for (int k0 = 0; k0 < 512; k0 += 64) {
    __syncthreads();
#pragma unroll
    for (int it = 0; it < 4; ++it) {
      int L = it * 256 + tid;
      int r = L >> 3, s = L & 7;
      int c = s ^ (r & 7);
      gload_lds16(A  + (size_t)(m0 + r) * 512 + k0 + c * 8,
                  (char*)As + (it * 256 + wid * 64) * 16);
      gload_lds16(Bt + (size_t)(n0 + r) * 512 + k0 + c * 8,
                  (char*)Bs + (it * 256 + wid * 64) * 16);
    }
    __syncthreads();
#pragma unroll
    for (int kh = 0; kh < 2; ++kh) {
      bf16x8 af[4], bfr[4];
#pragma unroll
      for (int m = 0; m < 4; ++m)
        af[m] = *(const bf16x8*)((const char*)As + aoff[kh] + m * 2048);
#pragma unroll
      for (int n = 0; n < 4; ++n)
        bfr[n] = *(const bf16x8*)((const char*)Bs + boff[kh] + n * 2048);
#pragma unroll
      for (int m = 0; m < 4; ++m)
#pragma unroll
        for (int n = 0; n < 4; ++n)
          acc[m][n] = __builtin_amdgcn_mfma_f32_16x16x32_bf16(af[m], bfr[n], acc[m][n], 0, 0, 0);
    }
  }

  const int gn0 = n0 + wc * 64 + l15;
  float bv[4];
#pragma unroll
  for (int n = 0; n < 4; ++n) bv[n] = bias[gn0 + n * 16];
#pragma unroll
  for (int m = 0; m < 4; ++m)
#pragma unroll
    for (int reg = 0; reg < 4; ++reg) {
      int gm = m0 + wr * 64 + m * 16 + lh * 4 + reg;
#pragma unroll
      for (int n = 0; n < 4; ++n)
        C[(size_t)gm * 512 + gn0 + n * 16] = acc[m][n][reg] + bv[n];
    }
}

// ---------------------------------------------------------------------------
// Window attention (bf16 in/out), fused q 5-tap smoothing. fp32 math.
// ---------------------------------------------------------------------------
__global__ __launch_bounds__(64) void attn_win(
    const u16* kp, const u16* vp, const u16* qp0, u16* attn)
{
  const int h = blockIdx.x, w = blockIdx.y, b = blockIdx.z;
  const int t = threadIdx.x;
  __shared__ float ks[8][68], vs[8][68], qr[12][68], qs[8][68], Ps[8][9];
  const size_t base = ((size_t)b * 4096 + (size_t)w * 8) * 512 + h * 64;

  {
    int i = t >> 3, dg = t & 7;
    u16x8 kv = *(const u16x8*)(kp + base + (size_t)i * 512 + dg * 8);
    u16x8 vv = *(const u16x8*)(vp + base + (size_t)i * 512 + dg * 8);
#pragma unroll
    for (int e = 0; e < 8; ++e) {
      ks[i][dg * 8 + e] = b2f(kv[e]);
      vs[i][dg * 8 + e] = b2f(vv[e]);
    }
  }
#pragma unroll
  for (int l = 0; l < 2; ++l) {
    int L = t + l * 64;
    if (L < 96) {
      int i = L >> 3, dg = L & 7;
      int m = w * 8 - 2 + i;
      if (m >= 0 && m < 4096) {
        u16x8 qv = *(const u16x8*)(qp0 + ((size_t)b * 4096 + m) * 512 + h * 64 + dg * 8);
#pragma unroll
        for (int e = 0; e < 8; ++e) qr[i][dg * 8 + e] = b2f(qv[e]);
      } else {
#pragma unroll
        for (int e = 0; e < 8; ++e) qr[i][dg * 8 + e] = 0.0f;
      }
    }
  }
  __syncthreads();
#pragma unroll
  for (int j = 0; j < 8; ++j)
    qs[j][t] = 0.2f * (qr[j][t] + qr[j + 1][t] + qr[j + 2][t] + qr[j + 3][t] + qr[j + 4][t]);
  __syncthreads();

  const int qi = t >> 3, kj = t & 7;
  float s = 0.0f;
#pragma unroll
  for (int d = 0; d < 64; ++d) s = fmaf(qs[qi][d], ks[kj][d], s);
  s *= SCALE_;
  float mx = s;
  mx = fmaxf(mx, __shfl_xor(mx, 1));
  mx = fmaxf(mx, __shfl_xor(mx, 2));
  mx = fmaxf(mx, __shfl_xor(mx, 4));
  float e = expf(s - mx);
  float sum = e;
  sum += __shfl_xor(sum, 1);
  sum += __shfl_xor(sum, 2);
  sum += __shfl_xor(sum, 4);
  Ps[qi][kj] = e / sum;
  __syncthreads();

  float o[8];
#pragma unroll
  for (int c = 0; c < 8; ++c) o[c] = 0.0f;
#pragma unroll
  for (int tt = 0; tt < 8; ++tt) {
    float pw = Ps[qi][tt];
#pragma unroll
    for (int c = 0; c < 8; ++c) o[c] = fmaf(pw, vs[tt][kj * 8 + c], o[c]);
  }
  u16x8 ov;
#pragma unroll
  for (int c = 0; c < 8; ++c) ov[c] = f2b(o[c]);
  *(u16x8*)(attn + base + (size_t)qi * 512 + kj * 8) = ov;
}

// ---------------------------------------------------------------------------
// Build pvT[bh][n=t*64+d][w2] = attn[b][8*w2+t+1][h*64+d]  (bf16)
// ---------------------------------------------------------------------------
__global__ __launch_bounds__(256) void pvt_build(const u16* attn, u16* pvT)
{
  const int bh = blockIdx.x;
  const int b = bh >> 3, h = bh & 7;
  const int w0 = blockIdx.y * 32;
  __shared__ u16 TL[448 * 40];
  const int tid = threadIdx.x;
#pragma unroll
  for (int it = 0; it < 8; ++it) {
    int L = it * 256 + tid;
    int dg = L & 7, r = L >> 3;
    int w2l = r >> 3, tt = r & 7;
    if (tt < 7) {
      int m = 8 * (w0 + w2l) + tt + 1;
      u16x8 v = *(const u16x8*)(attn + ((size_t)b * 4096 + m) * 512 + h * 64 + dg * 8);
#pragma unroll
      for (int e = 0; e < 8; ++e)
        TL[(tt * 64 + dg * 8 + e) * 40 + w2l] = v[e];
    }
  }
  __syncthreads();
#pragma unroll
  for (int it = 0; it < 7; ++it) {
    int L = it * 256 + tid;
    int n = L >> 2, seg = L & 3;
    u16x8 v = *(const u16x8*)(&TL[n * 40 + seg * 8]);
    *(u16x8*)(pvT + ((size_t)bh * 448 + n) * 512 + w0 + seg * 8) = v;
  }
}

// ---------------------------------------------------------------------------
// LayerNorm + exact GELU on window token 0 (bf16 in/out). One wave per row.
// ---------------------------------------------------------------------------
__global__ __launch_bounds__(64) void ln_gelu(
    const u16* attn, const float* g, const float* be, u16* wt)
{
  const int r = blockIdx.x;            // r = b*512 + w
  const int b = r >> 9, w = r & 511;
  const int t = threadIdx.x;
  const u16* x = attn + (((size_t)b * 4096) + (size_t)w * 8) * 512;

  u16x8 v = *(const u16x8*)(x + t * 8);
  float xv[8];
  float s1 = 0.f, s2 = 0.f;
#pragma unroll
  for (int e = 0; e < 8; ++e) {
    xv[e] = b2f(v[e]);
    s1 += xv[e]; s2 += xv[e] * xv[e];
  }
#pragma unroll
  for (int off = 1; off < 64; off <<= 1) {
    s1 += __shfl_xor(s1, off);
    s2 += __shfl_xor(s2, off);
  }
  const float mu  = s1 * (1.0f / 512.0f);
  const float var = s2 * (1.0f / 512.0f) - mu * mu;
  const float inv = 1.0f / sqrtf(var + EPS_);

  const int d0 = t * 8;
  float4 g0 = *reinterpret_cast<const float4*>(g + d0);
  float4 g1 = *reinterpret_cast<const float4*>(g + d0 + 4);
  float4 b0 = *reinterpret_cast<const float4*>(be + d0);
  float4 b1 = *reinterpret_cast<const float4*>(be + d0 + 4);
  float gv[8] = {g0.x, g0.y, g0.z, g0.w, g1.x, g1.y, g1.z, g1.w};
  float bvv[8] = {b0.x, b0.y, b0.z, b0.w, b1.x, b1.y, b1.z, b1.w};
  const float k2 = 0.70710678118654752f;
  u16x8 ov;
#pragma unroll
  for (int e = 0; e < 8; ++e) {
    float y = (xv[e] - mu) * inv * gv[e] + bvv[e];
    ov[e] = f2b(0.5f * y * (1.0f + erff(y * k2)));
  }
  *(u16x8*)(wt + (size_t)r * 512 + d0) = ov;
}

// ---------------------------------------------------------------------------
// expS[bh][wq][wk] = exp(SCALE * pq . pk) in bf16. fp32 inputs, 64x64 tiles.
// ---------------------------------------------------------------------------
__global__ __launch_bounds__(256) void qk_exp(
    const float* pq, const float* pk, u16* expS)
{
  const int bh = blockIdx.z;
  const int b = bh >> 3, h = bh & 7;
  const int wq0 = blockIdx.x * 64, wk0 = blockIdx.y * 64;
  const int tid = threadIdx.x;

  __shared__ float Aq[64][68];
  __shared__ float Bk[64][68];

#pragma unroll
  for (int l = 0; l < 4; ++l) {
    int L = tid + l * 256;
    int row = L >> 4, dv = L & 15;
    float4 a = *reinterpret_cast<const float4*>(pq + ((size_t)b * 512 + wq0 + row) * 512 + h * 64 + dv * 4);
    float4 c = *reinterpret_cast<const float4*>(pk + ((size_t)b * 512 + wk0 + row) * 512 + h * 64 + dv * 4);
    Aq[dv * 4 + 0][row] = a.x; Aq[dv * 4 + 1][row] = a.y;
    Aq[dv * 4 + 2][row] = a.z; Aq[dv * 4 + 3][row] = a.w;
    Bk[dv * 4 + 0][row] = c.x; Bk[dv * 4 + 1][row] = c.y;
    Bk[dv * 4 + 2][row] = c.z; Bk[dv * 4 + 3][row] = c.w;
  }
  __syncthreads();

  const int r0 = (tid >> 4) * 4, c0 = (tid & 15) * 4;
  float acc[4][4];
#pragma unroll
  for (int i = 0; i < 4; ++i)
#pragma unroll
    for (int j = 0; j < 4; ++j) acc[i][j] = 0.0f;

#pragma unroll
  for (int kk = 0; kk < 64; ++kk) {
    float4 a = *reinterpret_cast<const float4*>(&Aq[kk][r0]);
    float4 c = *reinterpret_cast<const float4*>(&Bk[kk][c0]);
    float av[4] = {a.x, a.y, a.z, a.w};
    float cv[4] = {c.x, c.y, c.z, c.w};
#pragma unroll
    for (int i = 0; i < 4; ++i)
#pragma unroll
      for (int j = 0; j < 4; ++j)
        acc[i][j] = fmaf(av[i], cv[j], acc[i][j]);
  }

#pragma unroll
  for (int i = 0; i < 4; ++i) {
    u16x4 o;
#pragma unroll
    for (int j = 0; j < 4; ++j) o[j] = f2b(expf(acc[i][j] * SCALE_));
    *(u16x4*)(expS + ((size_t)bh * 512 + wq0 + r0 + i) * 512 + wk0 + c0) = o;
  }
}

// ---------------------------------------------------------------------------
// rsinv[row] = 1 / sum_k expS[row][k]  (bf16 in). 4 rows per 256-thread block.
// ---------------------------------------------------------------------------
__global__ __launch_bounds__(256) void rs_inv(const u16* expS, float* rsinv)
{
  const int row = blockIdx.x * 4 + (threadIdx.x >> 6);
  const int t = threadIdx.x & 63;
  u16x8 v = *(const u16x8*)(expS + (size_t)row * 512 + t * 8);
  float s = 0.f;
#pragma unroll
  for (int e = 0; e < 8; ++e) s += b2f(v[e]);
#pragma unroll
  for (int off = 1; off < 64; off <<= 1) s += __shfl_xor(s, off);
  if (t == 0) rsinv[row] = 1.0f / s;
}

// ---------------------------------------------------------------------------
// PV MFMA GEMM + rescale + residual:
// X2[b][wq*7+t][h*64+d] = (sum_w2 expS[bh][wq][w2] * pvT[bh][t*64+d][w2]) *
//                         rsinv[bh*512+wq]  +  attn[b][8wq+t+1][h*64+d]
// ---------------------------------------------------------------------------
__global__ __launch_bounds__(256) void pv_mfma(
    const u16* __restrict__ expS, const u16* __restrict__ pvT,
    const float* __restrict__ rsinv, const u16* __restrict__ attn,
    u16* __restrict__ X2)
{
  __shared__ u16 As[8192];   // 128 x 64
  __shared__ u16 Bs[4096];   // 64 x 64
  const int tid = threadIdx.x;
  const int lane = tid & 63, wid = tid >> 6;
  const int wr = wid >> 1, wc = wid & 1;
  const int l15 = lane & 15, lh = lane >> 4, l7 = lane & 7;
  const int bh = blockIdx.z, b = bh >> 3, h = bh & 7;
  const int m0 = blockIdx.x * 128;
  const int nt = blockIdx.y;           // t in [0,7)

  const f32x4 fz = {0.f, 0.f, 0.f, 0.f};
  f32x4 acc[4][2];
#pragma unroll
  for (int m = 0; m < 4; ++m)
#pragma unroll
    for (int n = 0; n < 2; ++n) acc[m][n] = fz;

  int aoff[2], boff[2];
#pragma unroll
  for (int kh = 0; kh < 2; ++kh) {
    int slot = ((kh * 4 + lh) ^ l7) << 4;
    aoff[kh] = (wr * 64 + l15) * 128 + slot;
    boff[kh] = (wc * 32 + l15) * 128 + slot;
  }

  for (int k0 = 0; k0 < 512; k0 += 64) {
    __syncthreads();
#pragma unroll
    for (int it = 0; it < 4; ++it) {
      int L = it * 256 + tid;
      int r = L >> 3, s = L & 7;
      int c = s ^ (r & 7);
      gload_lds16(expS + ((size_t)bh * 512 + m0 + r) * 512 + k0 + c * 8,
                  (char*)As + (it * 256 + wid * 64) * 16);
    }
#pragma unroll
    for (int it = 0; it < 2; ++it) {
      int L = it * 256 + tid;
      int r = L >> 3, s = L & 7;
      int c = s ^ (r & 7);
      gload_lds16(pvT + ((size_t)bh * 448 + nt * 64 + r) * 512 + k0 + c * 8,
                  (char*)Bs + (it * 256 + wid * 64) * 16);
    }
    __syncthreads();
#pragma unroll
    for (int kh = 0; kh < 2; ++kh) {
      bf16x8 af[4], bfr[2];
#pragma unroll
      for (int m = 0; m < 4; ++m)
        af[m] = *(const bf16x8*)((const char*)As + aoff[kh] + m * 2048);
#pragma unroll
      for (int n = 0; n < 2; ++n)
        bfr[n] = *(const bf16x8*)((const char*)Bs + boff[kh] + n * 2048);
#pragma unroll
      for (int m = 0; m < 4; ++m)
#pragma unroll
        for (int n = 0; n < 2; ++n)
          acc[m][n] = __builtin_amdgcn_mfma_f32_16x16x32_bf16(af[m], bfr[n], acc[m][n], 0, 0, 0);
    }
  }

#pragma unroll
  for (int m = 0; m < 4; ++m)
#pragma unroll
    for (int reg = 0; reg < 4; ++reg) {
      int gm = m0 + wr * 64 + m * 16 + lh * 4 + reg;      // wq
      float ri = rsinv[bh * 512 + gm];
#pragma unroll
      for (int n = 0; n < 2; ++n) {
        int d = wc * 32 + n * 16 + l15;
        float res = b2f(attn[((size_t)b * 4096 + gm * 8 + nt + 1) * 512 + h * 64 + d]);
        X2[((size_t)b * 3584 + gm * 7 + nt) * 512 + h * 64 + d] =
            f2b(acc[m][n][reg] * ri + res);
      }
    }
}

// ---------------------------------------------------------------------------
extern "C" void kernel_launch(void* const* d_in, const int* in_sizes, int n_in,
                              void* d_out, int out_size, void* d_ws, size_t ws_size,
                              hipStream_t stream)
{
  const float* k_in = (const float*)d_in[0];
  const float* v_in = (const float*)d_in[1];
  const float* q_in = (const float*)d_in[2];
  const float* Wk  = (const float*)d_in[4];
  const float* bk  = (const float*)d_in[5];
  const float* Wv  = (const float*)d_in[6];
  const float* bv  = (const float*)d_in[7];
  const float* Wq  = (const float*)d_in[8];
  const float* bq  = (const float*)d_in[9];
  const float* lng = (const float*)d_in[10];
  const float* lnb = (const float*)d_in[11];
  const float* Wpq = (const float*)d_in[12];
  const float* bpq = (const float*)d_in[13];
  const float* Wpk = (const float*)d_in[14];
  const float* bpk = (const float*)d_in[15];
  const float* Wo  = (const float*)d_in[16];
  const float* bo  = (const float*)d_in[17];
  float* out = (float*)d_out;

  char* ws = (char*)d_ws;
  const size_t MB = 1024 * 1024;
  u16* wtb  = (u16*)(ws);                 // 6 x 512KB transposed bf16 weights
  u16* kp   = (u16*)(ws + 16 * MB);       // 34MB
  u16* vp   = (u16*)(ws + 52 * MB);       // 34MB
  u16* qp0  = (u16*)(ws + 88 * MB);       // 34MB
  u16* attn = (u16*)(ws + 124 * MB);      // 34MB
  // phase 2 (kp/vp/qp0 regions reused after attn_win)
  u16*   wt    = (u16*)(ws + 16 * MB);    // 4MB
  float* pq    = (float*)(ws + 20 * MB);  // 8MB
  float* pk    = (float*)(ws + 28 * MB);  // 8MB
  float* rsinv = (float*)(ws + 36 * MB);  // 128KB
  u16*   expS  = (u16*)(ws + 40 * MB);    // 34MB
  u16*   pvT   = (u16*)(ws + 76 * MB);    // 30MB
  u16*   X2    = (u16*)(ws + 160 * MB);   // 30MB

  u16* Wkt  = wtb;
  u16* Wvt  = wtb + 1 * 262144;
  u16* Wqt  = wtb + 2 * 262144;
  u16* Wpqt = wtb + 3 * 262144;
  u16* Wpkt = wtb + 4 * 262144;
  u16* Wot  = wtb + 5 * 262144;

  wconv<<<dim3(8, 8, 6), 256, 0, stream>>>(Wk, Wv, Wq, Wpq, Wpk, Wo, wtb);

  // fused fp32->bf16 + projection GEMMs (k, v, q), full-N strips
  gemm_proj<<<dim3(256, 1, 3), 512, 0, stream>>>(
      k_in, Wkt, bk, kp,
      v_in, Wvt, bv, vp,
      q_in, Wqt, bq, qp0);

  attn_win<<<dim3(8, 512, 8), 64, 0, stream>>>(kp, vp, qp0, attn);
  pvt_build<<<dim3(64, 16), 256, 0, stream>>>(attn, pvT);
  ln_gelu<<<4096, 64, 0, stream>>>(attn, lng, lnb, wt);

  gemm_pp<<<dim3(32, 4, 2), 256, 0, stream>>>(
      wt, Wpqt, bpq, pq, Wpkt, bpk, pk);

  qk_exp<<<dim3(8, 8, 64), 256, 0, stream>>>(pq, pk, expS);
  rs_inv<<<8192, 256, 0, stream>>>(expS, rsinv);
  pv_mfma<<<dim3(4, 7, 64), 256, 0, stream>>>(expS, pvT, rsinv, attn, X2);

  gemm_out<<<dim3(224, 1, 1), 512, 0, stream>>>(X2, Wot, bo, out);
}

// Round 5
// 281.143 us; speedup vs baseline: 4.2662x; 1.0715x over previous
//
#include <hip/hip_runtime.h>
#include <hip/hip_bf16.h>
#include <math.h>

#define SCALE_ 0.04419417382415922f   // 512^-0.5
#define EPS_  1e-5f

typedef unsigned short u16;
typedef __attribute__((ext_vector_type(8))) short     bf16x8;
typedef __attribute__((ext_vector_type(4))) float     f32x4;
typedef __attribute__((ext_vector_type(8))) unsigned short u16x8;
typedef __attribute__((ext_vector_type(4))) unsigned short u16x4;

__device__ __forceinline__ u16 f2b(float f) {
  union { float f; unsigned int u; } x; x.f = f;
  unsigned int u = x.u;
  return (u16)((u + 0x7FFFu + ((u >> 16) & 1u)) >> 16);
}
__device__ __forceinline__ float b2f(u16 h) {
  union { unsigned int u; float f; } x; x.u = ((unsigned int)h) << 16;
  return x.f;
}
__device__ __forceinline__ void gload_lds16(const void* g, void* l) {
  __builtin_amdgcn_global_load_lds(
      (const __attribute__((address_space(1))) void*)g,
      (__attribute__((address_space(3))) void*)l, 16, 0, 0);
}

// ---------------------------------------------------------------------------
// Weight convert+transpose: Wt[n][k] = bf16(W[k][n]), 512x512, z selects weight
// ---------------------------------------------------------------------------
__global__ __launch_bounds__(256) void wconv(
    const float* W0, const float* W1, const float* W2,
    const float* W3, const float* W4, const float* W5, u16* wt)
{
  const float* W;
  switch (blockIdx.z) {
    case 0: W = W0; break; case 1: W = W1; break; case 2: W = W2; break;
    case 3: W = W3; break; case 4: W = W4; break; default: W = W5; break;
  }
  u16* Wt = wt + (size_t)blockIdx.z * 262144;
  const int k0 = blockIdx.x * 64, n0 = blockIdx.y * 64;
  __shared__ float T[64][68];
  const int tid = threadIdx.x;
#pragma unroll
  for (int it = 0; it < 4; ++it) {
    int L = it * 256 + tid;
    int r = L >> 4, cg = L & 15;
    float4 v = *reinterpret_cast<const float4*>(W + (size_t)(k0 + r) * 512 + n0 + cg * 4);
    T[r][cg * 4 + 0] = v.x; T[r][cg * 4 + 1] = v.y;
    T[r][cg * 4 + 2] = v.z; T[r][cg * 4 + 3] = v.w;
  }
  __syncthreads();
#pragma unroll
  for (int it = 0; it < 2; ++it) {
    int L = it * 256 + tid;
    int rn = L >> 3, kg = L & 7;
    u16x8 o;
#pragma unroll
    for (int e = 0; e < 8; ++e) o[e] = f2b(T[kg * 8 + e][rn]);
    *(u16x8*)(Wt + (size_t)(n0 + rn) * 512 + k0 + kg * 8) = o;
  }
}

// ---------------------------------------------------------------------------
// Strip projection GEMM, double-buffered 2-phase pipeline:
// C_bf16[128 x 512 strip] = bf16(A_f32) @ Bt^T + bias.
// BK=32, 512 threads = 8 waves (2M x 4N). LDS 2x(8KB A + 32KB B) = 80KB.
// Slot swizzle: physical slot = s ^ ((row>>1)&3) (64B rows, 2-way banks).
// ---------------------------------------------------------------------------
__global__ __launch_bounds__(512) void gemm_proj(
    const float* A0, const u16* Bt0, const float* bi0, u16* C0,
    const float* A1, const u16* Bt1, const float* bi1, u16* C1,
    const float* A2, const u16* Bt2, const float* bi2, u16* C2)
{
  const float *A, *bias; const u16* Bt; u16* C;
  if (blockIdx.z == 0)      { A = A0; Bt = Bt0; bias = bi0; C = C0; }
  else if (blockIdx.z == 1) { A = A1; Bt = Bt1; bias = bi1; C = C1; }
  else                      { A = A2; Bt = Bt2; bias = bi2; C = C2; }

  __shared__ u16 As[2][4096];    // 128 rows x 32 k, 64B rows
  __shared__ u16 Bs[2][16384];   // 512 rows x 32 k
  const int tid = threadIdx.x;
  const int lane = tid & 63, wid = tid >> 6;
  const int wr = wid >> 2, wcn = wid & 3;          // 2 x 4 wave grid
  const int l15 = lane & 15, lh = lane >> 4;
  const int sx = (l15 >> 1) & 3;                   // read-side slot XOR
  const int m0 = blockIdx.x * 128;

  // staging indices: thread covers one 16B slot; rr = row, sp = physical slot
  const int rr = tid >> 2, sp = tid & 3;
  const int ssw = sp ^ ((rr >> 1) & 3);            // logical slot to fetch

  const f32x4 fz = {0.f, 0.f, 0.f, 0.f};
  f32x4 acc[4][8];
#pragma unroll
  for (int m = 0; m < 4; ++m)
#pragma unroll
    for (int n = 0; n < 8; ++n) acc[m][n] = fz;

  const int aoff0 = (wr * 64 + l15) * 64 + ((lh ^ sx) << 4);
  const int boff0 = (wcn * 128 + l15) * 64 + ((lh ^ sx) << 4);

  // prologue: stage k-tile 0 into buffer 0
  {
#pragma unroll
    for (int it = 0; it < 4; ++it)
      gload_lds16(Bt + (size_t)(it * 128 + rr) * 512 + ssw * 8,
                  (char*)Bs[0] + (it * 512 + wid * 64) * 16);
    const float* ga = A + (size_t)(m0 + rr) * 512 + ssw * 8;
    float4 x0 = *reinterpret_cast<const float4*>(ga);
    float4 x1 = *reinterpret_cast<const float4*>(ga + 4);
    u16x8 o;
    o[0] = f2b(x0.x); o[1] = f2b(x0.y); o[2] = f2b(x0.z); o[3] = f2b(x0.w);
    o[4] = f2b(x1.x); o[5] = f2b(x1.y); o[6] = f2b(x1.z); o[7] = f2b(x1.w);
    *(u16x8*)((char*)As[0] + tid * 16) = o;
  }
  __syncthreads();

#pragma unroll 2
  for (int t = 0; t < 16; ++t) {
    const int cur = t & 1, nxt = cur ^ 1;
    float4 x0 = {0.f,0.f,0.f,0.f}, x1 = {0.f,0.f,0.f,0.f};
    if (t < 15) {
      const int k0 = (t + 1) * 32;
#pragma unroll
      for (int it = 0; it < 4; ++it)
        gload_lds16(Bt + (size_t)(it * 128 + rr) * 512 + k0 + ssw * 8,
                    (char*)Bs[nxt] + (it * 512 + wid * 64) * 16);
      const float* ga = A + (size_t)(m0 + rr) * 512 + k0 + ssw * 8;
      x0 = *reinterpret_cast<const float4*>(ga);
      x1 = *reinterpret_cast<const float4*>(ga + 4);
    }
    // compute current buffer
    bf16x8 af[4], bfr[8];
#pragma unroll
    for (int m = 0; m < 4; ++m)
      af[m] = *(const bf16x8*)((const char*)As[cur] + aoff0 + m * 1024);
#pragma unroll
    for (int n = 0; n < 8; ++n)
      bfr[n] = *(const bf16x8*)((const char*)Bs[cur] + boff0 + n * 1024);
#pragma unroll
    for (int m = 0; m < 4; ++m)
#pragma unroll
      for (int n = 0; n < 8; ++n)
        acc[m][n] = __builtin_amdgcn_mfma_f32_16x16x32_bf16(af[m], bfr[n], acc[m][n], 0, 0, 0);
    if (t < 15) {
      u16x8 o;
      o[0] = f2b(x0.x); o[1] = f2b(x0.y); o[2] = f2b(x0.z); o[3] = f2b(x0.w);
      o[4] = f2b(x1.x); o[5] = f2b(x1.y); o[6] = f2b(x1.z); o[7] = f2b(x1.w);
      *(u16x8*)((char*)As[nxt] + tid * 16) = o;
    }
    __syncthreads();
  }

  const int gn0 = wcn * 128 + l15;
  float bv[8];
#pragma unroll
  for (int n = 0; n < 8; ++n) bv[n] = bias[gn0 + n * 16];
#pragma unroll
  for (int m = 0; m < 4; ++m)
#pragma unroll
    for (int reg = 0; reg < 4; ++reg) {
      int gm = m0 + wr * 64 + m * 16 + lh * 4 + reg;
#pragma unroll
      for (int n = 0; n < 8; ++n)
        C[(size_t)gm * 512 + gn0 + n * 16] = f2b(acc[m][n][reg] + bv[n]);
    }
}

// ---------------------------------------------------------------------------
// Strip output GEMM, double-buffered: out_f32 = A_bf16 @ Bt^T + bias.
// Same pipeline as gemm_proj; A staged via gload_lds (already bf16).
// ---------------------------------------------------------------------------
__global__ __launch_bounds__(512) void gemm_out(
    const u16* __restrict__ A, const u16* __restrict__ Bt,
    const float* __restrict__ bias, float* __restrict__ C)
{
  __shared__ u16 As[2][4096];
  __shared__ u16 Bs[2][16384];
  const int tid = threadIdx.x;
  const int lane = tid & 63, wid = tid >> 6;
  const int wr = wid >> 2, wcn = wid & 3;
  const int l15 = lane & 15, lh = lane >> 4;
  const int sx = (l15 >> 1) & 3;
  const int m0 = blockIdx.x * 128;
  const int rr = tid >> 2, sp = tid & 3;
  const int ssw = sp ^ ((rr >> 1) & 3);

  const f32x4 fz = {0.f, 0.f, 0.f, 0.f};
  f32x4 acc[4][8];
#pragma unroll
  for (int m = 0; m < 4; ++m)
#pragma unroll
    for (int n = 0; n < 8; ++n) acc[m][n] = fz;

  const int aoff0 = (wr * 64 + l15) * 64 + ((lh ^ sx) << 4);
  const int boff0 = (wcn * 128 + l15) * 64 + ((lh ^ sx) << 4);

  {
#pragma unroll
    for (int it = 0; it < 4; ++it)
      gload_lds16(Bt + (size_t)(it * 128 + rr) * 512 + ssw * 8,
                  (char*)Bs[0] + (it * 512 + wid * 64) * 16);
    gload_lds16(A + (size_t)(m0 + rr) * 512 + ssw * 8,
                (char*)As[0] + (wid * 64) * 16);
  }
  __syncthreads();

#pragma unroll 2
  for (int t = 0; t < 16; ++t) {
    const int cur = t & 1, nxt = cur ^ 1;
    if (t < 15) {
      const int k0 = (t + 1) * 32;
#pragma unroll
      for (int it = 0; it < 4; ++it)
        gload_lds16(Bt + (size_t)(it * 128 + rr) * 512 + k0 + ssw * 8,
                    (char*)Bs[nxt] + (it * 512 + wid * 64) * 16);
      gload_lds16(A + (size_t)(m0 + rr) * 512 + k0 + ssw * 8,
                  (char*)As[nxt] + (wid * 64) * 16);
    }
    bf16x8 af[4], bfr[8];
#pragma unroll
    for (int m = 0; m < 4; ++m)
      af[m] = *(const bf16x8*)((const char*)As[cur] + aoff0 + m * 1024);
#pragma unroll
    for (int n = 0; n < 8; ++n)
      bfr[n] = *(const bf16x8*)((const char*)Bs[cur] + boff0 + n * 1024);
#pragma unroll
    for (int m = 0; m < 4; ++m)
#pragma unroll
      for (int n = 0; n < 8; ++n)
        acc[m][n] = __builtin_amdgcn_mfma_f32_16x16x32_bf16(af[m], bfr[n], acc[m][n], 0, 0, 0);
    __syncthreads();
  }

  const int gn0 = wcn * 128 + l15;
  float bv[8];
#pragma unroll
  for (int n = 0; n < 8; ++n) bv[n] = bias[gn0 + n * 16];
#pragma unroll
  for (int m = 0; m < 4; ++m)
#pragma unroll
    for (int reg = 0; reg < 4; ++reg) {
      int gm = m0 + wr * 64 + m * 16 + lh * 4 + reg;
#pragma unroll
      for (int n = 0; n < 8; ++n)
        C[(size_t)gm * 512 + gn0 + n * 16] = acc[m][n][reg] + bv[n];
    }
}

// ---------------------------------------------------------------------------
// pq/pk GEMM (small): bf16 out now. 128x128 tiles, z selects set. Bt is [n][k].
// ---------------------------------------------------------------------------
__global__ __launch_bounds__(256) void gemm_pp(
    const u16* __restrict__ A,
    const u16* __restrict__ Bt0, const float* __restrict__ bi0, u16* __restrict__ C0,
    const u16* __restrict__ Bt1, const float* __restrict__ bi1, u16* __restrict__ C1)
{
  const u16* Bt; const float* bias; u16* C;
  if (blockIdx.z == 0) { Bt = Bt0; bias = bi0; C = C0; }
  else                 { Bt = Bt1; bias = bi1; C = C1; }

  __shared__ u16 As[8192];   // 128 x 64
  __shared__ u16 Bs[8192];   // 128 x 64
  const int tid = threadIdx.x;
  const int lane = tid & 63, wid = tid >> 6;
  const int wr = wid >> 1, wc = wid & 1;
  const int l15 = lane & 15, lh = lane >> 4, l7 = lane & 7;
  const int m0 = blockIdx.x * 128, n0 = blockIdx.y * 128;

  const f32x4 fz = {0.f, 0.f, 0.f, 0.f};
  f32x4 acc[4][4];
#pragma unroll
  for (int m = 0; m < 4; ++m)
#pragma unroll
    for (int n = 0; n < 4; ++n) acc[m][n] = fz;

  int aoff[2], boff[2];
#pragma unroll
  for (int kh = 0; kh < 2; ++kh) {
    int slot = ((kh * 4 + lh) ^ l7) << 4;
    aoff[kh] = (wr * 64 + l15) * 128 + slot;
    boff[kh] = (wc * 64 + l15) * 128 + slot;
  }

  for (int k0 = 0; k0 < 512; k0 += 64) {
    __syncthreads();
#pragma unroll
    for (int it = 0; it < 4; ++it) {
      int L = it * 256 + tid;
      int r = L >> 3, s = L & 7;
      int c = s ^ (r & 7);
      gload_lds16(A  + (size_t)(m0 + r) * 512 + k0 + c * 8,
                  (char*)As + (it * 256 + wid * 64) * 16);
      gload_lds16(Bt + (size_t)(n0 + r) * 512 + k0 + c * 8,
                  (char*)Bs + (it * 256 + wid * 64) * 16);
    }
    __syncthreads();
#pragma unroll
    for (int kh = 0; kh < 2; ++kh) {
      bf16x8 af[4], bfr[4];
#pragma unroll
      for (int m = 0; m < 4; ++m)
        af[m] = *(const bf16x8*)((const char*)As + aoff[kh] + m * 2048);
#pragma unroll
      for (int n = 0; n < 4; ++n)
        bfr[n] = *(const bf16x8*)((const char*)Bs + boff[kh] + n * 2048);
#pragma unroll
      for (int m = 0; m < 4; ++m)
#pragma unroll
        for (int n = 0; n < 4; ++n)
          acc[m][n] = __builtin_amdgcn_mfma_f32_16x16x32_bf16(af[m], bfr[n], acc[m][n], 0, 0, 0);
    }
  }

  const int gn0 = n0 + wc * 64 + l15;
  float bv[4];
#pragma unroll
  for (int n = 0; n < 4; ++n) bv[n] = bias[gn0 + n * 16];
#pragma unroll
  for (int m = 0; m < 4; ++m)
#pragma unroll
    for (int reg = 0; reg < 4; ++reg) {
      int gm = m0 + wr * 64 + m * 16 + lh * 4 + reg;
#pragma unroll
      for (int n = 0; n < 4; ++n)
        C[(size_t)gm * 512 + gn0 + n * 16] = f2b(acc[m][n][reg] + bv[n]);
    }
}

// ---------------------------------------------------------------------------
// qk_mfma: expS[bh][wq][wk] = exp(SCALE * pq_h[wq] . pk_h[wk]) via MFMA.
// pq/pk bf16 [b][wn][512] with head h at cols h*64. 128x128 tile, K=64.
// ---------------------------------------------------------------------------
__global__ __launch_bounds__(256) void qk_mfma(
    const u16* __restrict__ pq, const u16* __restrict__ pk, u16* __restrict__ expS)
{
  __shared__ u16 As[8192];   // 128 x 64
  __shared__ u16 Bs[8192];
  const int tid = threadIdx.x;
  const int lane = tid & 63, wid = tid >> 6;
  const int wr = wid >> 1, wc = wid & 1;
  const int l15 = lane & 15, lh = lane >> 4, l7 = lane & 7;
  const int bh = blockIdx.z, b = bh >> 3, h = bh & 7;
  const int wq0 = blockIdx.x * 128, wk0 = blockIdx.y * 128;

  const f32x4 fz = {0.f, 0.f, 0.f, 0.f};
  f32x4 acc[4][4];
#pragma unroll
  for (int m = 0; m < 4; ++m)
#pragma unroll
    for (int n = 0; n < 4; ++n) acc[m][n] = fz;

#pragma unroll
  for (int it = 0; it < 4; ++it) {
    int L = it * 256 + tid;
    int r = L >> 3, s = L & 7;
    int c = s ^ (r & 7);
    gload_lds16(pq + ((size_t)b * 512 + wq0 + r) * 512 + h * 64 + c * 8,
                (char*)As + (it * 256 + wid * 64) * 16);
    gload_lds16(pk + ((size_t)b * 512 + wk0 + r) * 512 + h * 64 + c * 8,
                (char*)Bs + (it * 256 + wid * 64) * 16);
  }
  __syncthreads();

#pragma unroll
  for (int kh = 0; kh < 2; ++kh) {
    int slot = ((kh * 4 + lh) ^ l7) << 4;
    int aoff = (wr * 64 + l15) * 128 + slot;
    int boff = (wc * 64 + l15) * 128 + slot;
    bf16x8 af[4], bfr[4];
#pragma unroll
    for (int m = 0; m < 4; ++m)
      af[m] = *(const bf16x8*)((const char*)As + aoff + m * 2048);
#pragma unroll
    for (int n = 0; n < 4; ++n)
      bfr[n] = *(const bf16x8*)((const char*)Bs + boff + n * 2048);
#pragma unroll
    for (int m = 0; m < 4; ++m)
#pragma unroll
      for (int n = 0; n < 4; ++n)
        acc[m][n] = __builtin_amdgcn_mfma_f32_16x16x32_bf16(af[m], bfr[n], acc[m][n], 0, 0, 0);
  }

  const int gn0 = wk0 + wc * 64 + l15;
#pragma unroll
  for (int m = 0; m < 4; ++m)
#pragma unroll
    for (int reg = 0; reg < 4; ++reg) {
      int gm = wq0 + wr * 64 + m * 16 + lh * 4 + reg;
#pragma unroll
      for (int n = 0; n < 4; ++n)
        expS[((size_t)bh * 512 + gm) * 512 + gn0 + n * 16] =
            f2b(expf(acc[m][n][reg] * SCALE_));
    }
}

// ---------------------------------------------------------------------------
// Window attention (bf16 in/out), fused q 5-tap smoothing. fp32 math.
// ---------------------------------------------------------------------------
__global__ __launch_bounds__(64) void attn_win(
    const u16* kp, const u16* vp, const u16* qp0, u16* attn)
{
  const int h = blockIdx.x, w = blockIdx.y, b = blockIdx.z;
  const int t = threadIdx.x;
  __shared__ float ks[8][68], vs[8][68], qr[12][68], qs[8][68], Ps[8][9];
  const size_t base = ((size_t)b * 4096 + (size_t)w * 8) * 512 + h * 64;

  {
    int i = t >> 3, dg = t & 7;
    u16x8 kv = *(const u16x8*)(kp + base + (size_t)i * 512 + dg * 8);
    u16x8 vv = *(const u16x8*)(vp + base + (size_t)i * 512 + dg * 8);
#pragma unroll
    for (int e = 0; e < 8; ++e) {
      ks[i][dg * 8 + e] = b2f(kv[e]);
      vs[i][dg * 8 + e] = b2f(vv[e]);
    }
  }
#pragma unroll
  for (int l = 0; l < 2; ++l) {
    int L = t + l * 64;
    if (L < 96) {
      int i = L >> 3, dg = L & 7;
      int m = w * 8 - 2 + i;
      if (m >= 0 && m < 4096) {
        u16x8 qv = *(const u16x8*)(qp0 + ((size_t)b * 4096 + m) * 512 + h * 64 + dg * 8);
#pragma unroll
        for (int e = 0; e < 8; ++e) qr[i][dg * 8 + e] = b2f(qv[e]);
      } else {
#pragma unroll
        for (int e = 0; e < 8; ++e) qr[i][dg * 8 + e] = 0.0f;
      }
    }
  }
  __syncthreads();
#pragma unroll
  for (int j = 0; j < 8; ++j)
    qs[j][t] = 0.2f * (qr[j][t] + qr[j + 1][t] + qr[j + 2][t] + qr[j + 3][t] + qr[j + 4][t]);
  __syncthreads();

  const int qi = t >> 3, kj = t & 7;
  float s = 0.0f;
#pragma unroll
  for (int d = 0; d < 64; ++d) s = fmaf(qs[qi][d], ks[kj][d], s);
  s *= SCALE_;
  float mx = s;
  mx = fmaxf(mx, __shfl_xor(mx, 1));
  mx = fmaxf(mx, __shfl_xor(mx, 2));
  mx = fmaxf(mx, __shfl_xor(mx, 4));
  float e = expf(s - mx);
  float sum = e;
  sum += __shfl_xor(sum, 1);
  sum += __shfl_xor(sum, 2);
  sum += __shfl_xor(sum, 4);
  Ps[qi][kj] = e / sum;
  __syncthreads();

  float o[8];
#pragma unroll
  for (int c = 0; c < 8; ++c) o[c] = 0.0f;
#pragma unroll
  for (int tt = 0; tt < 8; ++tt) {
    float pw = Ps[qi][tt];
#pragma unroll
    for (int c = 0; c < 8; ++c) o[c] = fmaf(pw, vs[tt][kj * 8 + c], o[c]);
  }
  u16x8 ov;
#pragma unroll
  for (int c = 0; c < 8; ++c) ov[c] = f2b(o[c]);
  *(u16x8*)(attn + base + (size_t)qi * 512 + kj * 8) = ov;
}

// ---------------------------------------------------------------------------
// Build pvT[bh][n=t*64+d][w2] = attn[b][8*w2+t+1][h*64+d]  (bf16)
// ---------------------------------------------------------------------------
__global__ __launch_bounds__(256) void pvt_build(const u16* attn, u16* pvT)
{
  const int bh = blockIdx.x;
  const int b = bh >> 3, h = bh & 7;
  const int w0 = blockIdx.y * 32;
  __shared__ u16 TL[448 * 40];
  const int tid = threadIdx.x;
#pragma unroll
  for (int it = 0; it < 8; ++it) {
    int L = it * 256 + tid;
    int dg = L & 7, r = L >> 3;
    int w2l = r >> 3, tt = r & 7;
    if (tt < 7) {
      int m = 8 * (w0 + w2l) + tt + 1;
      u16x8 v = *(const u16x8*)(attn + ((size_t)b * 4096 + m) * 512 + h * 64 + dg * 8);
#pragma unroll
      for (int e = 0; e < 8; ++e)
        TL[(tt * 64 + dg * 8 + e) * 40 + w2l] = v[e];
    }
  }
  __syncthreads();
#pragma unroll
  for (int it = 0; it < 7; ++it) {
    int L = it * 256 + tid;
    int n = L >> 2, seg = L & 3;
    u16x8 v = *(const u16x8*)(&TL[n * 40 + seg * 8]);
    *(u16x8*)(pvT + ((size_t)bh * 448 + n) * 512 + w0 + seg * 8) = v;
  }
}

// ---------------------------------------------------------------------------
// LayerNorm + exact GELU on window token 0 (bf16 in/out). One wave per row.
// ---------------------------------------------------------------------------
__global__ __launch_bounds__(64) void ln_gelu(
    const u16* attn, const float* g, const float* be, u16* wt)
{
  const int r = blockIdx.x;            // r = b*512 + w
  const int b = r >> 9, w = r & 511;
  const int t = threadIdx.x;
  const u16* x = attn + (((size_t)b * 4096) + (size_t)w * 8) * 512;

  u16x8 v = *(const u16x8*)(x + t * 8);
  float xv[8];
  float s1 = 0.f, s2 = 0.f;
#pragma unroll
  for (int e = 0; e < 8; ++e) {
    xv[e] = b2f(v[e]);
    s1 += xv[e]; s2 += xv[e] * xv[e];
  }
#pragma unroll
  for (int off = 1; off < 64; off <<= 1) {
    s1 += __shfl_xor(s1, off);
    s2 += __shfl_xor(s2, off);
  }
  const float mu  = s1 * (1.0f / 512.0f);
  const float var = s2 * (1.0f / 512.0f) - mu * mu;
  const float inv = 1.0f / sqrtf(var + EPS_);

  const int d0 = t * 8;
  float4 g0 = *reinterpret_cast<const float4*>(g + d0);
  float4 g1 = *reinterpret_cast<const float4*>(g + d0 + 4);
  float4 b0 = *reinterpret_cast<const float4*>(be + d0);
  float4 b1 = *reinterpret_cast<const float4*>(be + d0 + 4);
  float gv[8] = {g0.x, g0.y, g0.z, g0.w, g1.x, g1.y, g1.z, g1.w};
  float bvv[8] = {b0.x, b0.y, b0.z, b0.w, b1.x, b1.y, b1.z, b1.w};
  const float k2 = 0.70710678118654752f;
  u16x8 ov;
#pragma unroll
  for (int e = 0; e < 8; ++e) {
    float y = (xv[e] - mu) * inv * gv[e] + bvv[e];
    ov[e] = f2b(0.5f * y * (1.0f + erff(y * k2)));
  }
  *(u16x8*)(wt + (size_t)r * 512 + d0) = ov;
}

// ---------------------------------------------------------------------------
// rsinv[row] = 1 / sum_k expS[row][k]  (bf16 in). 4 rows per 256-thread block.
// ---------------------------------------------------------------------------
__global__ __launch_bounds__(256) void rs_inv(const u16* expS, float* rsinv)
{
  const int row = blockIdx.x * 4 + (threadIdx.x >> 6);
  const int t = threadIdx.x & 63;
  u16x8 v = *(const u16x8*)(expS + (size_t)row * 512 + t * 8);
  float s = 0.f;
#pragma unroll
  for (int e = 0; e < 8; ++e) s += b2f(v[e]);
#pragma unroll
  for (int off = 1; off < 64; off <<= 1) s += __shfl_xor(s, off);
  if (t == 0) rsinv[row] = 1.0f / s;
}

// ---------------------------------------------------------------------------
// PV MFMA GEMM + rescale + residual:
// X2[b][wq*7+t][h*64+d] = (sum_w2 expS[bh][wq][w2] * pvT[bh][t*64+d][w2]) *
//                         rsinv[bh*512+wq]  +  attn[b][8wq+t+1][h*64+d]
// ---------------------------------------------------------------------------
__global__ __launch_bounds__(256) void pv_mfma(
    const u16* __restrict__ expS, const u16* __restrict__ pvT,
    const float* __restrict__ rsinv, const u16* __restrict__ attn,
    u16* __restrict__ X2)
{
  __shared__ u16 As[8192];   // 128 x 64
  __shared__ u16 Bs[4096];   // 64 x 64
  const int tid = threadIdx.x;
  const int lane = tid & 63, wid = tid >> 6;
  const int wr = wid >> 1, wc = wid & 1;
  const int l15 = lane & 15, lh = lane >> 4, l7 = lane & 7;
  const int bh = blockIdx.z, b = bh >> 3, h = bh & 7;
  const int m0 = blockIdx.x * 128;
  const int nt = blockIdx.y;           // t in [0,7)

  const f32x4 fz = {0.f, 0.f, 0.f, 0.f};
  f32x4 acc[4][2];
#pragma unroll
  for (int m = 0; m < 4; ++m)
#pragma unroll
    for (int n = 0; n < 2; ++n) acc[m][n] = fz;

  int aoff[2], boff[2];
#pragma unroll
  for (int kh = 0; kh < 2; ++kh) {
    int slot = ((kh * 4 + lh) ^ l7) << 4;
    aoff[kh] = (wr * 64 + l15) * 128 + slot;
    boff[kh] = (wc * 32 + l15) * 128 + slot;
  }

  for (int k0 = 0; k0 < 512; k0 += 64) {
    __syncthreads();
#pragma unroll
    for (int it = 0; it < 4; ++it) {
      int L = it * 256 + tid;
      int r = L >> 3, s = L & 7;
      int c = s ^ (r & 7);
      gload_lds16(expS + ((size_t)bh * 512 + m0 + r) * 512 + k0 + c * 8,
                  (char*)As + (it * 256 + wid * 64) * 16);
    }
#pragma unroll
    for (int it = 0; it < 2; ++it) {
      int L = it * 256 + tid;
      int r = L >> 3, s = L & 7;
      int c = s ^ (r & 7);
      gload_lds16(pvT + ((size_t)bh * 448 + nt * 64 + r) * 512 + k0 + c * 8,
                  (char*)Bs + (it * 256 + wid * 64) * 16);
    }
    __syncthreads();
#pragma unroll
    for (int kh = 0; kh < 2; ++kh) {
      bf16x8 af[4], bfr[2];
#pragma unroll
      for (int m = 0; m < 4; ++m)
        af[m] = *(const bf16x8*)((const char*)As + aoff[kh] + m * 2048);
#pragma unroll
      for (int n = 0; n < 2; ++n)
        bfr[n] = *(const bf16x8*)((const char*)Bs + boff[kh] + n * 2048);
#pragma unroll
      for (int m = 0; m < 4; ++m)
#pragma unroll
        for (int n = 0; n < 2; ++n)
          acc[m][n] = __builtin_amdgcn_mfma_f32_16x16x32_bf16(af[m], bfr[n], acc[m][n], 0, 0, 0);
    }
  }

#pragma unroll
  for (int m = 0; m < 4; ++m)
#pragma unroll
    for (int reg = 0; reg < 4; ++reg) {
      int gm = m0 + wr * 64 + m * 16 + lh * 4 + reg;      // wq
      float ri = rsinv[bh * 512 + gm];
#pragma unroll
      for (int n = 0; n < 2; ++n) {
        int d = wc * 32 + n * 16 + l15;
        float res = b2f(attn[((size_t)b * 4096 + gm * 8 + nt + 1) * 512 + h * 64 + d]);
        X2[((size_t)b * 3584 + gm * 7 + nt) * 512 + h * 64 + d] =
            f2b(acc[m][n][reg] * ri + res);
      }
    }
}

// ---------------------------------------------------------------------------
extern "C" void kernel_launch(void* const* d_in, const int* in_sizes, int n_in,
                              void* d_out, int out_size, void* d_ws, size_t ws_size,
                              hipStream_t stream)
{
  const float* k_in = (const float*)d_in[0];
  const float* v_in = (const float*)d_in[1];
  const float* q_in = (const float*)d_in[2];
  const float* Wk  = (const float*)d_in[4];
  const float* bk  = (const float*)d_in[5];
  const float* Wv  = (const float*)d_in[6];
  const float* bv  = (const float*)d_in[7];
  const float* Wq  = (const float*)d_in[8];
  const float* bq  = (const float*)d_in[9];
  const float* lng = (const float*)d_in[10];
  const float* lnb = (const float*)d_in[11];
  const float* Wpq = (const float*)d_in[12];
  const float* bpq = (const float*)d_in[13];
  const float* Wpk = (const float*)d_in[14];
  const float* bpk = (const float*)d_in[15];
  const float* Wo  = (const float*)d_in[16];
  const float* bo  = (const float*)d_in[17];
  float* out = (float*)d_out;

  char* ws = (char*)d_ws;
  const size_t MB = 1024 * 1024;
  u16* wtb  = (u16*)(ws);                 // 6 x 512KB transposed bf16 weights
  u16* kp   = (u16*)(ws + 16 * MB);       // 34MB
  u16* vp   = (u16*)(ws + 52 * MB);       // 34MB
  u16* qp0  = (u16*)(ws + 88 * MB);       // 34MB
  u16* attn = (u16*)(ws + 124 * MB);      // 34MB
  // phase 2 (kp/vp/qp0 regions reused after attn_win)
  u16*   wt    = (u16*)(ws + 16 * MB);    // 4MB
  u16*   pq    = (u16*)(ws + 20 * MB);    // 4MB (bf16 now)
  u16*   pk    = (u16*)(ws + 28 * MB);    // 4MB
  float* rsinv = (float*)(ws + 36 * MB);  // 128KB
  u16*   expS  = (u16*)(ws + 40 * MB);    // 34MB
  u16*   pvT   = (u16*)(ws + 76 * MB);    // 30MB
  u16*   X2    = (u16*)(ws + 160 * MB);   // 30MB

  u16* Wkt  = wtb;
  u16* Wvt  = wtb + 1 * 262144;
  u16* Wqt  = wtb + 2 * 262144;
  u16* Wpqt = wtb + 3 * 262144;
  u16* Wpkt = wtb + 4 * 262144;
  u16* Wot  = wtb + 5 * 262144;

  wconv<<<dim3(8, 8, 6), 256, 0, stream>>>(Wk, Wv, Wq, Wpq, Wpk, Wo, wtb);

  // fused fp32->bf16 + projection GEMMs (k, v, q), full-N strips, dbuf
  gemm_proj<<<dim3(256, 1, 3), 512, 0, stream>>>(
      k_in, Wkt, bk, kp,
      v_in, Wvt, bv, vp,
      q_in, Wqt, bq, qp0);

  attn_win<<<dim3(8, 512, 8), 64, 0, stream>>>(kp, vp, qp0, attn);
  pvt_build<<<dim3(64, 16), 256, 0, stream>>>(attn, pvT);
  ln_gelu<<<4096, 64, 0, stream>>>(attn, lng, lnb, wt);

  gemm_pp<<<dim3(32, 4, 2), 256, 0, stream>>>(
      wt, Wpqt, bpq, pq, Wpkt, bpk, pk);

  qk_mfma<<<dim3(4, 4, 64), 256, 0, stream>>>(pq, pk, expS);
  rs_inv<<<8192, 256, 0, stream>>>(expS, rsinv);
  pv_mfma<<<dim3(4, 7, 64), 256, 0, stream>>>(expS, pvT, rsinv, attn, X2);

  gemm_out<<<dim3(224, 1, 1), 512, 0, stream>>>(X2, Wot, bo, out);
}